// Round 11
// baseline (504.290 us; speedup 1.0000x reference)
//
#include <hip/hip_runtime.h>
#include <stdint.h>

typedef __bf16 bf16_t;
typedef __bf16 bf16x8 __attribute__((ext_vector_type(8)));
typedef __bf16 bf16x4 __attribute__((ext_vector_type(4)));
typedef float f32x4 __attribute__((ext_vector_type(4)));
typedef float f32x16 __attribute__((ext_vector_type(16)));
typedef unsigned int u32x4 __attribute__((ext_vector_type(4)));

#define DEV static __device__ __forceinline__

// problem constants
#define SB 2
#define SS 2048
#define SD 2048
#define SNQ 16
#define SNKV 8
#define SH 256
#define SWIN 1024
#define KVP 4096

DEV void async_ld16(const void* g, void* lds) {
  __builtin_amdgcn_global_load_lds(
      (const __attribute__((address_space(1))) void*)g,
      (__attribute__((address_space(3))) void*)lds, 16, 0, 0);
}

// ---------------------------------------------------------------- convert x
__global__ __launch_bounds__(256) void cvt_kernel(const float* __restrict__ in,
                                                  bf16_t* __restrict__ out) {
  int i = blockIdx.x * 256 + threadIdx.x;  // over n/4 elements
  float4 v = ((const float4*)in)[i];
  bf16x4 o = {(bf16_t)v.x, (bf16_t)v.y, (bf16_t)v.z, (bf16_t)v.w};
  *(bf16x4*)(out + (size_t)i * 4) = o;
}

// ------------------------------------------- batched transpose f32 -> bf16
__global__ __launch_bounds__(256) void wtrans_kernel(const float* __restrict__ in,
                                                     bf16_t* __restrict__ out,
                                                     int R, int C) {
  __shared__ float tile[32][33];
  const int bz = blockIdx.z;
  const float* ip = in + (size_t)bz * R * C;
  bf16_t* op = out + (size_t)bz * R * C;
  const int r0 = blockIdx.y * 32, c0 = blockIdx.x * 32;
  const int tr = threadIdx.x >> 5, tc = threadIdx.x & 31;
#pragma unroll
  for (int i = 0; i < 4; ++i)
    tile[tr + i * 8][tc] = ip[(size_t)(r0 + tr + i * 8) * C + c0 + tc];
  __syncthreads();
#pragma unroll
  for (int i = 0; i < 4; ++i)
    op[(size_t)(c0 + tr + i * 8) * R + r0 + tc] = (bf16_t)tile[tc][tr + i * 8];
}

// ------------------------------------------------- V transpose bf16 -> bf16
// kvpre [B*S][4096] (V half starts at col 2048)  ->  vt [B][NKV][H][S]
__global__ __launch_bounds__(256) void vtrans_kernel(const bf16_t* __restrict__ vbase,
                                                     bf16_t* __restrict__ vt) {
  __shared__ bf16_t tile[32][33];
  const int bz = blockIdx.z;           // b*8+kv
  const int b = bz >> 3, kv = bz & 7;
  const int t0 = blockIdx.y * 32, h0 = blockIdx.x * 32;
  const int tr = threadIdx.x >> 5, tc = threadIdx.x & 31;
  const bf16_t* ip = vbase + (size_t)b * SS * KVP + kv * SH;
#pragma unroll
  for (int i = 0; i < 4; ++i)
    tile[tr + i * 8][tc] = ip[(size_t)(t0 + tr + i * 8) * KVP + h0 + tc];
  __syncthreads();
  bf16_t* op = vt + (size_t)bz * SH * SS;
#pragma unroll
  for (int i = 0; i < 4; ++i)
    op[(size_t)(h0 + tr + i * 8) * SS + t0 + tc] = tile[tc][tr + i * 8];
}

// --------------------------------------------------------- RoPE-K (vector)
__global__ __launch_bounds__(256) void rope_k_kernel(const bf16_t* __restrict__ kpre,
                                                     bf16_t* __restrict__ kb) {
  int idx = blockIdx.x * 256 + threadIdx.x;      // B*S*NKV*16
  const int i8 = (idx & 15) << 3;                // 0..120
  const int kv = (idx >> 4) & 7;
  const int row = idx >> 7;                      // 0..4095
  const int t = row & (SS - 1), b = row >> 11;
  const size_t ib = (size_t)row * KVP + kv * SH;
  bf16x8 x1 = *(const bf16x8*)(kpre + ib + i8);
  bf16x8 x2 = *(const bf16x8*)(kpre + ib + i8 + 128);
  bf16x8 r1, r2;
#pragma unroll
  for (int e = 0; e < 8; ++e) {
    float c_ = (float)(i8 + e);
    float inv = __expf(c_ * -0.07195578f);       // ln(10000)/128
    float fr = (float)t * inv;
    float cs = __cosf(fr), sn = __sinf(fr);
    float a = (float)x1[e], b2 = (float)x2[e];
    r1[e] = (bf16_t)(a * cs - b2 * sn);
    r2[e] = (bf16_t)(b2 * cs + a * sn);
  }
  const size_t ob = ((size_t)(b * SNKV + kv) * SS + t) * SH;
  *(bf16x8*)(kb + ob + i8) = r1;
  *(bf16x8*)(kb + ob + i8 + 128) = r2;
}

// ------------------------------------------------------------------- GEMM
// C[M][N] = A[M][K] * Bt[N][K]^T ; 256 x (NBW*64) tile, BK=32, 8 waves.
// 4-deep LDS ring, counted vmcnt (T4), setprio around MFMA (T5).
template <int NBW, bool OUT_BF16>
__global__ __launch_bounds__(512, 2) void gemm_bt(const bf16_t* __restrict__ A,
                                                  const bf16_t* __restrict__ Bt,
                                                  void* __restrict__ Cout,
                                                  int M, int N, int K) {
  constexpr int BN = NBW * 64;
  constexpr int MFR = (256 / (8 / NBW)) / 16;   // m-frags per wave (8 or 4)
  constexpr int ALOADS = 2;
  constexpr int BLOADS = NBW / 2;
  constexpr int LT = ALOADS + BLOADS;
  __shared__ bf16_t As[4][256 * 32];
  __shared__ bf16_t Bs[4][BN * 32];

  const int tid = threadIdx.x, lane = tid & 63, wid = tid >> 6;
  const int nbx = N / BN;
  const int nwg = (M >> 8) * nbx;
  const int cpx = nwg >> 3;
  const int lb = (blockIdx.x & 7) * cpx + (blockIdx.x >> 3);  // XCD chunking
  const int bx = lb % nbx, by = lb / nbx;
  const int row0 = by << 8;
  const int col0 = bx * BN;
  const int wr = wid / NBW, wc = wid % NBW;
  const int lr = lane & 15, hi = lane >> 4;

  const bf16_t* Arow = A + (size_t)row0 * K;
  const bf16_t* Brow = Bt + (size_t)col0 * K;

  auto stageA = [&](int t) {
    const int k0 = t << 5;
#pragma unroll
    for (int it = 0; it < ALOADS; ++it) {
      const int f = tid + (it << 9);
      async_ld16(Arow + (size_t)(f >> 2) * K + k0 + ((f & 3) << 3),
                 (char*)As[t & 3] + f * 16);
    }
  };
  auto stageB = [&](int t) {
    const int k0 = t << 5;
#pragma unroll
    for (int it = 0; it < BLOADS; ++it) {
      const int f = tid + (it << 9);
      async_ld16(Brow + (size_t)(f >> 2) * K + k0 + ((f & 3) << 3),
                 (char*)Bs[t & 3] + f * 16);
    }
  };

  f32x4 acc[MFR][4];
#pragma unroll
  for (int m = 0; m < MFR; ++m)
#pragma unroll
    for (int n = 0; n < 4; ++n) acc[m][n] = f32x4{0.f, 0.f, 0.f, 0.f};

  const int NT = K >> 5;
  stageA(0); stageB(0); stageA(1); stageB(1); stageA(2); stageB(2);
  asm volatile("s_waitcnt vmcnt(%0)" ::"i"(2 * LT) : "memory");
  __builtin_amdgcn_s_barrier();
  __builtin_amdgcn_sched_barrier(0);

  for (int t = 0; t < NT; ++t) {
    const bf16_t* Ab = &As[t & 3][(wr * (MFR * 16)) * 32];
    const bf16_t* Bb = &Bs[t & 3][(wc * 64) * 32];
    const bool pre = (t + 3 < NT);

    bf16x8 bfr[4];
#pragma unroll
    for (int nf = 0; nf < 4; ++nf)
      bfr[nf] = *(const bf16x8*)&Bb[(nf * 16 + lr) * 32 + hi * 8];

#pragma unroll
    for (int ph = 0; ph < MFR / 4; ++ph) {
      if (pre && ph == 0) stageA(t + 3);
      if (pre && ph == (MFR / 4) - 1) stageB(t + 3);
      bf16x8 af[4];
#pragma unroll
      for (int mf = 0; mf < 4; ++mf)
        af[mf] = *(const bf16x8*)&Ab[((ph * 4 + mf) * 16 + lr) * 32 + hi * 8];
      __builtin_amdgcn_s_setprio(1);
#pragma unroll
      for (int mf = 0; mf < 4; ++mf)
#pragma unroll
        for (int nf = 0; nf < 4; ++nf)
          acc[ph * 4 + mf][nf] = __builtin_amdgcn_mfma_f32_16x16x32_bf16(
              af[mf], bfr[nf], acc[ph * 4 + mf][nf], 0, 0, 0);
      __builtin_amdgcn_s_setprio(0);
    }

    if (t + 3 < NT) {
      asm volatile("s_waitcnt vmcnt(%0)" ::"i"(2 * LT) : "memory");
    } else if (t + 2 < NT) {
      asm volatile("s_waitcnt vmcnt(%0)" ::"i"(LT) : "memory");
    } else if (t + 1 < NT) {
      asm volatile("s_waitcnt vmcnt(0)" ::: "memory");
    }
    if (t + 1 < NT) {
      __builtin_amdgcn_s_barrier();
      __builtin_amdgcn_sched_barrier(0);
    }
  }

#pragma unroll
  for (int mf = 0; mf < MFR; ++mf) {
    const int r = row0 + wr * (MFR * 16) + mf * 16 + hi * 4;
#pragma unroll
    for (int nf = 0; nf < 4; ++nf) {
      const int c = col0 + wc * 64 + nf * 16 + lr;
#pragma unroll
      for (int j = 0; j < 4; ++j) {
        if (OUT_BF16)
          ((bf16_t*)Cout)[(size_t)(r + j) * N + c] = (bf16_t)acc[mf][nf][j];
        else
          ((float*)Cout)[(size_t)(r + j) * N + c] = acc[mf][nf][j];
      }
    }
  }
}

// -------------------------------------------------------------- attention
// Swapped-QK 32x32 flash (m214/HK structure, H-split for H=256):
// 8 waves = 4 row-groups x 32 q-rows, x2 H-halves (QK duplicated per pair).
// QK: S^T = mfma_32x32x16(A=K, B=Q) -> lane holds P[q=lane&31][32 kv].
// Fixed-base softmax is lane-local (no max, no cross-lane). P -> PV A-frags
// via 16 v_cvt_pk_bf16_f32 + 8 v_permlane32_swap_b32 (lane l, l+32 hold same
// q, complementary kv) -- P never touches LDS, no mid-tile barrier.
// LDS tiled layouts [blk][chunk][row32]x16B: 32 lanes hit 32 consecutive
// 16B slots -> conflict-free by construction, no XOR (DMA dest = f*16).
// Registers/wave: arch = qf 64 + w/pa 32 + temps (<=128);
//                 acc = o 64 + sacc 32 = 96 (<=128). No spill.
#define QB 128
#define KVB 64

__global__ __launch_bounds__(512, 1) void attn_kernel(
    const bf16_t* __restrict__ Q,   // [B*S][NQ*H] (RAW projection output)
    const bf16_t* __restrict__ Kt,  // [B][NKV][S][H] (roped)
    const bf16_t* __restrict__ Vt,  // [B][NKV][H][S]
    bf16_t* __restrict__ AV) {      // [B*S][NQ*H]
  __shared__ bf16_t Ks[2][KVB * SH];   // 2 x 32 KB, tiled [kvb2][c32][row32]
  __shared__ bf16_t Vs[2][SH * KVB];   // 2 x 32 KB, tiled [hb8][c8][row32]

  const int tid = threadIdx.x, lane = tid & 63, wid = tid >> 6;
  const int grp = wid & 3;             // row-group (32 q rows)
  const int half = wid >> 2;           // H-half 0..1
  // LPT + XCD-locality decode (XCD x owns kvh=x)
  const int x = blockIdx.x & 7;
  const int y = blockIdx.x >> 3;       // 0..63
  const int qt = 15 - (y & 15);        // heavy q-tiles dispatch first
  const int head = (x << 1) | ((y >> 4) & 1);
  const int b = y >> 5;
  const int kvh = x;
  const int t0 = qt << 7;
  const int trw = t0 + grp * 32;       // group's first q row
  const int qcol = lane & 31;          // q within group (QK) / h-col (PV)
  const int lhi = lane >> 5;

  // Q load (B-frag layout: col=q=lane&31, k-slice by lhi) + fused RoPE + 1/16
  bf16x8 qf[16];
  {
    const bf16_t* qp = Q + ((size_t)(b * SS + trw + qcol)) * (SNQ * SH) + head * SH + lhi * 8;
#pragma unroll
    for (int hs = 0; hs < 16; ++hs) qf[hs] = *(const bf16x8*)(qp + hs * 16);
    const float tpos = (float)(trw + qcol);
#pragma unroll
    for (int hs = 0; hs < 8; ++hs) {
      bf16x8 a = qf[hs], b2 = qf[hs + 8];
      bf16x8 ra, rb;
#pragma unroll
      for (int e = 0; e < 8; ++e) {
        float c_ = (float)(hs * 16 + lhi * 8 + e);
        float inv = __expf(c_ * -0.07195578f);
        float fr = tpos * inv;
        float cs = __cosf(fr), sn = __sinf(fr);
        float x1 = (float)a[e], x2 = (float)b2[e];
        ra[e] = (bf16_t)((x1 * cs - x2 * sn) * 0.0625f);
        rb[e] = (bf16_t)((x2 * cs + x1 * sn) * 0.0625f);
      }
      qf[hs] = ra; qf[hs + 8] = rb;
    }
  }

  f32x16 o0, o1, o2, o3;
  o0 = o1 = o2 = o3 = (f32x16)(0.f);
  float lsum = 0.f;

  const bf16_t* Kb = Kt + (size_t)(b * SNKV + kvh) * SS * SH;
  const bf16_t* Vb = Vt + (size_t)(b * SNKV + kvh) * SH * SS;

  const int sv0 = (t0 >= SWIN) ? ((t0 >> 6) - 16) : 0;
  const int sv1 = (t0 >> 6) + 1;

  // DMA-stage K + V^T into buf d (tiled layouts; dest linear f*16).
  auto stage = [&](int s0, int d) {
#pragma unroll
    for (int it = 0; it < 4; ++it) {
      const int f = tid + (it << 9);           // 0..2047
      {
        const int kvb = f >> 10, c = (f >> 5) & 31, row = f & 31;
        async_ld16(Kb + (size_t)(s0 + kvb * 32 + row) * SH + c * 8,
                   (char*)Ks[d] + f * 16);
      }
      {
        const int hb = f >> 8, c = (f >> 5) & 7, row = f & 31;
        async_ld16(Vb + (size_t)(hb * 32 + row) * SS + s0 + c * 8,
                   (char*)Vs[d] + f * 16);
      }
    }
  };

  stage(sv0 << 6, 0);
  __syncthreads();

  int cur = 0;
  for (int sv = sv0; sv <= sv1; ++sv, cur ^= 1) {
    if (sv < sv1) stage((sv + 1) << 6, cur ^ 1);

    const int s0 = sv << 6;
    const bool skip = (s0 > trw + 31) || (s0 + 63 < trw - (SWIN - 1));
    if (!skip) {
      const bool full = (s0 + 63 <= trw) && (s0 >= trw + 31 - (SWIN - 1));
      const char* Kc = (const char*)Ks[cur];
      const char* Vc = (const char*)Vs[cur];

      // S^T = K . Q^T  (2 kv-blocks of 32)
      f32x16 sacc0 = (f32x16)(0.f), sacc1 = (f32x16)(0.f);
      __builtin_amdgcn_s_setprio(1);
#pragma unroll
      for (int hs = 0; hs < 16; ++hs) {
        const int c = hs * 2 + lhi;
        bf16x8 kf0 = *(const bf16x8*)(Kc + ((c * 32 + qcol) << 4));
        bf16x8 kf1 = *(const bf16x8*)(Kc + (((1024 + c * 32) + qcol) << 4));
        sacc0 = __builtin_amdgcn_mfma_f32_32x32x16_bf16(kf0, qf[hs], sacc0, 0, 0, 0);
        sacc1 = __builtin_amdgcn_mfma_f32_32x32x16_bf16(kf1, qf[hs], sacc1, 0, 0, 0);
      }
      __builtin_amdgcn_s_setprio(0);

      // softcap + exp (fixed base) + pack; lane-local. kv for reg r:
      // (r&3) + 8*(r>>2) + 4*lhi + 32*b2; q = trw + qcol.
      unsigned int w[16];
      const int qg = trw + qcol;
#pragma unroll
      for (int b2 = 0; b2 < 2; ++b2) {
        const f32x16 sa = b2 ? sacc1 : sacc0;
#pragma unroll
        for (int t = 0; t < 8; ++t) {
          float u0 = sa[2 * t] * 0.04f;
          float u1 = sa[2 * t + 1] * 0.04f;
          float th0 = 50.f - 100.f * __builtin_amdgcn_rcpf(__expf(u0) + 1.f);
          float th1 = 50.f - 100.f * __builtin_amdgcn_rcpf(__expf(u1) + 1.f);
          float p0 = __expf(th0), p1 = __expf(th1);
          if (!full) {
            const int kv0 = s0 + b2 * 32 + ((2 * t) & 3) + 8 * (t >> 1) + 4 * lhi;
            p0 = ((kv0 <= qg) && (qg - kv0 < SWIN)) ? p0 : 0.f;
            p1 = ((kv0 + 1 <= qg) && (qg - kv0 - 1 < SWIN)) ? p1 : 0.f;
          }
          lsum += p0 + p1;
          unsigned int wv;
          asm("v_cvt_pk_bf16_f32 %0, %1, %2" : "=v"(wv) : "v"(p0), "v"(p1));
          w[b2 * 8 + t] = wv;
        }
      }

      // P -> A-frags: permlane32_swap pairs (w[t], w[t+2]); lane l & l+32
      // hold the same q with complementary kv -> one swap fills two words.
      bf16x8 pa[4];
#pragma unroll
      for (int ks = 0; ks < 4; ++ks) {
        const int base = (ks >> 1) * 8 + (ks & 1) * 4;
        unsigned int a0 = w[base + 0], a2 = w[base + 2];
        unsigned int a1 = w[base + 1], a3 = w[base + 3];
        asm("v_permlane32_swap_b32 %0, %1" : "+v"(a0), "+v"(a2));
        asm("v_permlane32_swap_b32 %0, %1" : "+v"(a1), "+v"(a3));
        union { u32x4 u; bf16x8 h; } cv;
        cv.u = u32x4{a0, a1, a2, a3};
        pa[ks] = cv.h;
      }

      // O += P V for this wave's H-half (4 h-blocks of 32)
      __builtin_amdgcn_s_setprio(1);
#pragma unroll
      for (int ks = 0; ks < 4; ++ks) {
        const int c = ks * 2 + lhi;
        const int hbase = half * 4;
        bf16x8 vf0 = *(const bf16x8*)(Vc + ((((hbase + 0) * 8 + c) * 32 + qcol) << 4));
        bf16x8 vf1 = *(const bf16x8*)(Vc + ((((hbase + 1) * 8 + c) * 32 + qcol) << 4));
        bf16x8 vf2 = *(const bf16x8*)(Vc + ((((hbase + 2) * 8 + c) * 32 + qcol) << 4));
        bf16x8 vf3 = *(const bf16x8*)(Vc + ((((hbase + 3) * 8 + c) * 32 + qcol) << 4));
        o0 = __builtin_amdgcn_mfma_f32_32x32x16_bf16(pa[ks], vf0, o0, 0, 0, 0);
        o1 = __builtin_amdgcn_mfma_f32_32x32x16_bf16(pa[ks], vf1, o1, 0, 0, 0);
        o2 = __builtin_amdgcn_mfma_f32_32x32x16_bf16(pa[ks], vf2, o2, 0, 0, 0);
        o3 = __builtin_amdgcn_mfma_f32_32x32x16_bf16(pa[ks], vf3, o3, 0, 0, 0);
      }
      __builtin_amdgcn_s_setprio(0);
    }

    __syncthreads();  // drains DMA, frees buf[cur]
  }

  // row-sum: partner lane (l^32) holds the other 32 kv of the same q
  const float tot = lsum + __shfl_xor(lsum, 32);
  const float linv = 1.f / tot;

  // store: o reg r -> q-row (r&3)+8*(r>>2)+4*lhi, h-col = qcol (+hb*32)
#pragma unroll
  for (int r = 0; r < 16; ++r) {
    const int rowq = (r & 3) + 8 * (r >> 2) + 4 * lhi;
    const float inv = __shfl(linv, rowq);
    bf16_t* op = AV + ((size_t)(b * SS + trw + rowq)) * (SNQ * SH) + head * SH +
                 half * 128 + qcol;
    op[0]  = (bf16_t)(o0[r] * inv);
    op[32] = (bf16_t)(o1[r] * inv);
    op[64] = (bf16_t)(o2[r] * inv);
    op[96] = (bf16_t)(o3[r] * inv);
  }
}

// ------------------------------------------------------------------- host
extern "C" void kernel_launch(void* const* d_in, const int* in_sizes, int n_in,
                              void* d_out, int out_size, void* d_ws, size_t ws_size,
                              hipStream_t stream) {
  const float* x = (const float*)d_in[0];
  const float* Wq = (const float*)d_in[1];
  const float* Wk = (const float*)d_in[2];
  const float* Wv = (const float*)d_in[3];
  const float* Wo = (const float*)d_in[4];
  float* out = (float*)d_out;

  char* ws = (char*)d_ws;
  size_t off = 0;
  auto alloc = [&](size_t elems) {
    bf16_t* p = (bf16_t*)(ws + off);
    off += ((elems * 2 + 255) & ~(size_t)255);
    return p;
  };
  const size_t MS = (size_t)SB * SS;        // 4096 rows
  bf16_t* xb    = alloc(MS * SD);                 // [4096][2048]
  bf16_t* wqT   = alloc((size_t)SNQ * SH * SD);   // [4096][2048]
  bf16_t* wkvT  = alloc((size_t)2 * SNKV * SH * SD); // K rows then V rows
  bf16_t* woT   = alloc((size_t)SD * SNQ * SH);   // [2048][4096]
  bf16_t* qb    = alloc(MS * SNQ * SH);           // [4096][4096]
  bf16_t* kvpre = alloc(MS * 2 * SNKV * SH);      // [4096][4096] K | V cols
  bf16_t* kb    = alloc(MS * SNKV * SH);          // [B][NKV][S][H]
  bf16_t* vt    = alloc(MS * SNKV * SH);          // [B][NKV][H][S]
  bf16_t* av    = alloc(MS * SNQ * SH);           // [4096][4096]
  (void)ws_size;  // ~218 MB

  cvt_kernel<<<(MS * SD / 4) / 256, 256, 0, stream>>>(x, xb);
  wtrans_kernel<<<dim3(8, 64, 16), 256, 0, stream>>>(Wq, wqT, SD, SH);
  wtrans_kernel<<<dim3(8, 64, 8), 256, 0, stream>>>(Wk, wkvT, SD, SH);
  wtrans_kernel<<<dim3(8, 64, 8), 256, 0, stream>>>(Wv, wkvT + (size_t)SNKV * SH * SD, SD, SH);
  wtrans_kernel<<<dim3(64, 128, 1), 256, 0, stream>>>(Wo, woT, SNQ * SH, SD);

  gemm_bt<4, true><<<256, 512, 0, stream>>>(xb, wqT, qb, 4096, 4096, 2048);
  gemm_bt<4, true><<<256, 512, 0, stream>>>(xb, wkvT, kvpre, 4096, 4096, 2048);

  rope_k_kernel<<<(MS * SNKV * 16) / 256, 256, 0, stream>>>(kvpre, kb);
  vtrans_kernel<<<dim3(8, 64, 16), 256, 0, stream>>>(kvpre + 2048, vt);

  attn_kernel<<<512, 512, 0, stream>>>(qb, kb, vt, av);

  gemm_bt<2, false><<<256, 512, 0, stream>>>(av, woT, out, 4096, 2048, 4096);
}

// Round 12
// 460.581 us; speedup vs baseline: 1.0949x; 1.0949x over previous
//
#include <hip/hip_runtime.h>
#include <stdint.h>

typedef __bf16 bf16_t;
typedef __bf16 bf16x8 __attribute__((ext_vector_type(8)));
typedef __bf16 bf16x4 __attribute__((ext_vector_type(4)));
typedef float f32x4 __attribute__((ext_vector_type(4)));

#define DEV static __device__ __forceinline__

// problem constants
#define SB 2
#define SS 2048
#define SD 2048
#define SNQ 16
#define SNKV 8
#define SH 256
#define SWIN 1024
#define KVP 4096

DEV void async_ld16(const void* g, void* lds) {
  __builtin_amdgcn_global_load_lds(
      (const __attribute__((address_space(1))) void*)g,
      (__attribute__((address_space(3))) void*)lds, 16, 0, 0);
}

// ---------------------------------------------------------------- convert x
__global__ __launch_bounds__(256) void cvt_kernel(const float* __restrict__ in,
                                                  bf16_t* __restrict__ out) {
  int i = blockIdx.x * 256 + threadIdx.x;  // over n/4 elements
  float4 v = ((const float4*)in)[i];
  bf16x4 o = {(bf16_t)v.x, (bf16_t)v.y, (bf16_t)v.z, (bf16_t)v.w};
  *(bf16x4*)(out + (size_t)i * 4) = o;
}

// ------------------------------------------- batched transpose f32 -> bf16
// in [BZ][R][C] f32 -> out [BZ][C][R] bf16. 64x64 tiles, vector global
// access both directions (16B/lane), transpose via LDS (144B pitch + XOR).
__global__ __launch_bounds__(256) void wtrans_kernel(const float* __restrict__ in,
                                                     bf16_t* __restrict__ out,
                                                     int R, int C) {
  __shared__ bf16_t T[64 * 72];
  const int bz = blockIdx.z;
  const float* ip = in + (size_t)bz * R * C;
  bf16_t* op = out + (size_t)bz * R * C;
  const int r0 = blockIdx.y * 64, c0 = blockIdx.x * 64;
  const int tc = threadIdx.x & 15;        // 16 x 4 f32 = 64 cols
  const int tr = threadIdx.x >> 4;        // 0..15
#pragma unroll
  for (int i = 0; i < 4; ++i) {
    const int r = tr + i * 16;
    float4 v = *(const float4*)(ip + (size_t)(r0 + r) * C + c0 + tc * 4);
    float vv[4] = {v.x, v.y, v.z, v.w};
#pragma unroll
    for (int e = 0; e < 4; ++e) {
      const int row = tc * 4 + e;         // transposed row (= input col)
      *(bf16_t*)((char*)T + row * 144 + ((r * 2) ^ (((row >> 3) & 7) << 4))) =
          (bf16_t)vv[e];
    }
  }
  __syncthreads();
  const int tc2 = threadIdx.x & 7, tr2 = threadIdx.x >> 3;  // 0..31
#pragma unroll
  for (int i = 0; i < 2; ++i) {
    const int row = tr2 + i * 32;
    bf16x8 v = *(const bf16x8*)((const char*)T + row * 144 +
                                ((tc2 * 16) ^ (((row >> 3) & 7) << 4)));
    *(bf16x8*)(op + (size_t)(c0 + row) * R + r0 + tc2 * 8) = v;
  }
}

// ------------------------------------------------- V transpose bf16 -> bf16
// kvpre [B*S][4096] (V at +2048) -> vt [b*8+kv][H][S]. 64x64 tiles,
// vector global both directions, LDS transpose (144B pitch + XOR).
__global__ __launch_bounds__(256) void vtrans_kernel(const bf16_t* __restrict__ vbase,
                                                     bf16_t* __restrict__ vt) {
  __shared__ bf16_t T[64 * 72];
  const int bz = blockIdx.z, b = bz >> 3, kv = bz & 7;
  const int t0 = blockIdx.y * 64, h0 = blockIdx.x * 64;
  const int tc = threadIdx.x & 7, tr = threadIdx.x >> 3;  // tr 0..31
  const bf16_t* ip = vbase + (size_t)b * SS * KVP + kv * SH;
#pragma unroll
  for (int i = 0; i < 2; ++i) {
    const int t = tr + i * 32;
    bf16x8 v = *(const bf16x8*)(ip + (size_t)(t0 + t) * KVP + h0 + tc * 8);
#pragma unroll
    for (int e = 0; e < 8; ++e) {
      const int row = tc * 8 + e;         // h-row in transposed tile
      *(bf16_t*)((char*)T + row * 144 + ((t * 2) ^ (((row >> 3) & 7) << 4))) = v[e];
    }
  }
  __syncthreads();
  bf16_t* op = vt + (size_t)bz * SH * SS;
#pragma unroll
  for (int i = 0; i < 2; ++i) {
    const int row = tr + i * 32;
    bf16x8 v = *(const bf16x8*)((const char*)T + row * 144 +
                                ((tc * 16) ^ (((row >> 3) & 7) << 4)));
    *(bf16x8*)(op + (size_t)(h0 + row) * SS + t0 + tc * 8) = v;
  }
}

// --------------------------------------------------------- RoPE-K (vector)
__global__ __launch_bounds__(256) void rope_k_kernel(const bf16_t* __restrict__ kpre,
                                                     bf16_t* __restrict__ kb) {
  int idx = blockIdx.x * 256 + threadIdx.x;      // B*S*NKV*16
  const int i8 = (idx & 15) << 3;                // 0..120
  const int kv = (idx >> 4) & 7;
  const int row = idx >> 7;                      // 0..4095
  const int t = row & (SS - 1), b = row >> 11;
  const size_t ib = (size_t)row * KVP + kv * SH;
  bf16x8 x1 = *(const bf16x8*)(kpre + ib + i8);
  bf16x8 x2 = *(const bf16x8*)(kpre + ib + i8 + 128);
  bf16x8 r1, r2;
#pragma unroll
  for (int e = 0; e < 8; ++e) {
    float c_ = (float)(i8 + e);
    float inv = __expf(c_ * -0.07195578f);       // ln(10000)/128
    float fr = (float)t * inv;
    float cs = __cosf(fr), sn = __sinf(fr);
    float a = (float)x1[e], b2 = (float)x2[e];
    r1[e] = (bf16_t)(a * cs - b2 * sn);
    r2[e] = (bf16_t)(b2 * cs + a * sn);
  }
  const size_t ob = ((size_t)(b * SNKV + kv) * SS + t) * SH;
  *(bf16x8*)(kb + ob + i8) = r1;
  *(bf16x8*)(kb + ob + i8 + 128) = r2;
}

// ------------------------------------------------------------------- GEMM
// C[M][N] = A[M][K] * Bt[N][K]^T ; 256 x (NBW*64) tile, BK=32, 8 waves.
// 4-deep LDS ring, counted vmcnt (T4), setprio around MFMA (T5).
template <int NBW, bool OUT_BF16>
__global__ __launch_bounds__(512, 2) void gemm_bt(const bf16_t* __restrict__ A,
                                                  const bf16_t* __restrict__ Bt,
                                                  void* __restrict__ Cout,
                                                  int M, int N, int K) {
  constexpr int BN = NBW * 64;
  constexpr int MFR = (256 / (8 / NBW)) / 16;   // m-frags per wave (8 or 4)
  constexpr int ALOADS = 2;
  constexpr int BLOADS = NBW / 2;
  constexpr int LT = ALOADS + BLOADS;
  __shared__ bf16_t As[4][256 * 32];
  __shared__ bf16_t Bs[4][BN * 32];

  const int tid = threadIdx.x, lane = tid & 63, wid = tid >> 6;
  const int nbx = N / BN;
  const int nwg = (M >> 8) * nbx;
  const int cpx = nwg >> 3;
  const int lb = (blockIdx.x & 7) * cpx + (blockIdx.x >> 3);  // XCD chunking
  const int bx = lb % nbx, by = lb / nbx;
  const int row0 = by << 8;
  const int col0 = bx * BN;
  const int wr = wid / NBW, wc = wid % NBW;
  const int lr = lane & 15, hi = lane >> 4;

  const bf16_t* Arow = A + (size_t)row0 * K;
  const bf16_t* Brow = Bt + (size_t)col0 * K;

  auto stageA = [&](int t) {
    const int k0 = t << 5;
#pragma unroll
    for (int it = 0; it < ALOADS; ++it) {
      const int f = tid + (it << 9);
      async_ld16(Arow + (size_t)(f >> 2) * K + k0 + ((f & 3) << 3),
                 (char*)As[t & 3] + f * 16);
    }
  };
  auto stageB = [&](int t) {
    const int k0 = t << 5;
#pragma unroll
    for (int it = 0; it < BLOADS; ++it) {
      const int f = tid + (it << 9);
      async_ld16(Brow + (size_t)(f >> 2) * K + k0 + ((f & 3) << 3),
                 (char*)Bs[t & 3] + f * 16);
    }
  };

  f32x4 acc[MFR][4];
#pragma unroll
  for (int m = 0; m < MFR; ++m)
#pragma unroll
    for (int n = 0; n < 4; ++n) acc[m][n] = f32x4{0.f, 0.f, 0.f, 0.f};

  const int NT = K >> 5;
  stageA(0); stageB(0); stageA(1); stageB(1); stageA(2); stageB(2);
  asm volatile("s_waitcnt vmcnt(%0)" ::"i"(2 * LT) : "memory");
  __builtin_amdgcn_s_barrier();
  __builtin_amdgcn_sched_barrier(0);

  for (int t = 0; t < NT; ++t) {
    const bf16_t* Ab = &As[t & 3][(wr * (MFR * 16)) * 32];
    const bf16_t* Bb = &Bs[t & 3][(wc * 64) * 32];
    const bool pre = (t + 3 < NT);

    bf16x8 bfr[4];
#pragma unroll
    for (int nf = 0; nf < 4; ++nf)
      bfr[nf] = *(const bf16x8*)&Bb[(nf * 16 + lr) * 32 + hi * 8];

#pragma unroll
    for (int ph = 0; ph < MFR / 4; ++ph) {
      if (pre && ph == 0) stageA(t + 3);
      if (pre && ph == (MFR / 4) - 1) stageB(t + 3);
      bf16x8 af[4];
#pragma unroll
      for (int mf = 0; mf < 4; ++mf)
        af[mf] = *(const bf16x8*)&Ab[((ph * 4 + mf) * 16 + lr) * 32 + hi * 8];
      __builtin_amdgcn_s_setprio(1);
#pragma unroll
      for (int mf = 0; mf < 4; ++mf)
#pragma unroll
        for (int nf = 0; nf < 4; ++nf)
          acc[ph * 4 + mf][nf] = __builtin_amdgcn_mfma_f32_16x16x32_bf16(
              af[mf], bfr[nf], acc[ph * 4 + mf][nf], 0, 0, 0);
      __builtin_amdgcn_s_setprio(0);
    }

    if (t + 3 < NT) {
      asm volatile("s_waitcnt vmcnt(%0)" ::"i"(2 * LT) : "memory");
    } else if (t + 2 < NT) {
      asm volatile("s_waitcnt vmcnt(%0)" ::"i"(LT) : "memory");
    } else if (t + 1 < NT) {
      asm volatile("s_waitcnt vmcnt(0)" ::: "memory");
    }
    if (t + 1 < NT) {
      __builtin_amdgcn_s_barrier();
      __builtin_amdgcn_sched_barrier(0);
    }
  }

#pragma unroll
  for (int mf = 0; mf < MFR; ++mf) {
    const int r = row0 + wr * (MFR * 16) + mf * 16 + hi * 4;
#pragma unroll
    for (int nf = 0; nf < 4; ++nf) {
      const int c = col0 + wc * 64 + nf * 16 + lr;
#pragma unroll
      for (int j = 0; j < 4; ++j) {
        if (OUT_BF16)
          ((bf16_t*)Cout)[(size_t)(r + j) * N + c] = (bf16_t)acc[mf][nf][j];
        else
          ((float*)Cout)[(size_t)(r + j) * N + c] = acc[mf][nf][j];
      }
    }
  }
}

// -------------------------------------------------------------- attention
// R7 geometry (proven best math) at 2 blocks/CU: single-buffered K/V +
// swizzled 16KB Ps -> LDS = 80KB exactly. Stage->drain->compute is serial
// within a block; the co-resident block covers the drain (m97-GEMM TLP
// mechanism). 8 waves x 16 q-rows, KVB=64, fixed-base softmax, RoPE-Q
// fused into the Q load. Swizzles: K chunk^=(row&7) (both sides);
// V chunk^=(row&7) (both sides); Ps byte ^= (row&7)<<4 at 128B pitch.
#define QB 128
#define KVB 64

__global__ __launch_bounds__(512, 2) void attn_kernel(
    const bf16_t* __restrict__ Q,   // [B*S][NQ*H] (RAW projection output)
    const bf16_t* __restrict__ Kt,  // [B][NKV][S][H] (roped)
    const bf16_t* __restrict__ Vt,  // [B][NKV][H][S]
    bf16_t* __restrict__ AV) {      // [B*S][NQ*H]
  __shared__ bf16_t Ks[KVB * SH];      // 32 KB, row pitch 512B
  __shared__ bf16_t Vs[SH * KVB];      // 32 KB, row pitch 128B
  __shared__ bf16_t Ps[QB * 64];       // 16 KB, row pitch 128B (swizzled)

  const int tid = threadIdx.x, lane = tid & 63, wid = tid >> 6;
  // LPT + XCD-locality decode (XCD x owns kvh=x)
  const int x = blockIdx.x & 7;
  const int y = blockIdx.x >> 3;       // 0..63
  const int qt = 15 - (y & 15);        // heavy q-tiles dispatch first
  const int head = (x << 1) | ((y >> 4) & 1);
  const int b = y >> 5;
  const int kvh = x;
  const int t0 = qt << 7;
  const int trw = t0 + wid * 16;       // this wave's first q row
  const int lr = lane & 15, hi = lane >> 4;
  const int lk = hi << 3;
  const int lq = hi;

  // Q load + fused RoPE + 1/16 scale (pair (c, c+128) = qf[ks], qf[ks+4])
  bf16x8 qf[8];
  {
    const bf16_t* qp = Q + ((size_t)(b * SS + trw + lr)) * (SNQ * SH) + head * SH + lk;
#pragma unroll
    for (int ks = 0; ks < 8; ++ks) qf[ks] = *(const bf16x8*)(qp + ks * 32);
    const float tpos = (float)(trw + lr);
#pragma unroll
    for (int ks = 0; ks < 4; ++ks) {
      bf16x8 a = qf[ks], b2 = qf[ks + 4];
      bf16x8 ra, rb;
#pragma unroll
      for (int e = 0; e < 8; ++e) {
        float c_ = (float)(ks * 32 + lk + e);
        float inv = __expf(c_ * -0.07195578f);
        float fr = tpos * inv;
        float cs = __cosf(fr), sn = __sinf(fr);
        float x1 = (float)a[e], x2 = (float)b2[e];
        ra[e] = (bf16_t)((x1 * cs - x2 * sn) * 0.0625f);
        rb[e] = (bf16_t)((x2 * cs + x1 * sn) * 0.0625f);
      }
      qf[ks] = ra; qf[ks + 4] = rb;
    }
  }

  f32x4 o[16];
#pragma unroll
  for (int i = 0; i < 16; ++i) o[i] = f32x4{0.f, 0.f, 0.f, 0.f};
  float lsum[4] = {0.f, 0.f, 0.f, 0.f};

  const bf16_t* Kb = Kt + (size_t)(b * SNKV + kvh) * SS * SH;
  const bf16_t* Vb = Vt + (size_t)(b * SNKV + kvh) * SH * SS;

  const int sv0 = (t0 >= SWIN) ? ((t0 >> 6) - 16) : 0;
  const int sv1 = (t0 >> 6) + 1;

  // DMA-stage K (64x256) + V^T (256x64); both-sides XOR swizzle.
  auto stage = [&](int s0) {
#pragma unroll
    for (int it = 0; it < 4; ++it) {
      const int f = tid + (it << 9);           // 0..2047
      {
        const int r = f >> 5, pc = f & 31;
        const int sc = pc ^ (r & 7);
        async_ld16(Kb + (size_t)(s0 + r) * SH + sc * 8, (char*)Ks + f * 16);
      }
      {
        const int r = f >> 3, pc = f & 7;
        const int sc = pc ^ (r & 7);
        async_ld16(Vb + (size_t)r * SS + s0 + sc * 8, (char*)Vs + f * 16);
      }
    }
  };

  for (int sv = sv0; sv <= sv1; ++sv) {
    stage(sv << 6);
    __syncthreads();  // drains DMA (vmcnt 0) -> buffers ready

    const int s0 = sv << 6;
    const bool skip = (s0 > trw + 15) || (s0 + 63 < trw - (SWIN - 1));
    if (!skip) {
      // S = Q K^T (4 col-frags of 16)
      f32x4 sacc[4];
#pragma unroll
      for (int nt = 0; nt < 4; ++nt) sacc[nt] = f32x4{0.f, 0.f, 0.f, 0.f};
      __builtin_amdgcn_s_setprio(1);
#pragma unroll
      for (int ks = 0; ks < 8; ++ks) {
#pragma unroll
        for (int nt = 0; nt < 4; ++nt) {
          const int R = nt * 16 + lr;
          bf16x8 kf = *(const bf16x8*)((const char*)Ks + R * 512 +
                                       (((ks * 4 + hi) ^ (R & 7)) << 4));
          sacc[nt] = __builtin_amdgcn_mfma_f32_16x16x32_bf16(qf[ks], kf, sacc[nt], 0, 0, 0);
        }
      }
      __builtin_amdgcn_s_setprio(0);

      // softcap + exp (fixed base), write P (swizzled 128B-pitch rows)
      const bool full = (s0 + 63 <= trw) && (s0 >= trw + 15 - (SWIN - 1));
#pragma unroll
      for (int nt = 0; nt < 4; ++nt) {
#pragma unroll
        for (int j = 0; j < 4; ++j) {
          float u = sacc[nt][j] * 0.04f;
          float th = 50.f - 100.f * __builtin_amdgcn_rcpf(__expf(u) + 1.f);
          float p;
          if (full) {
            p = __expf(th);
          } else {
            const int s_ = s0 + nt * 16 + lr;
            const int t_ = trw + lq * 4 + j;
            const bool valid = (s_ <= t_) && (t_ - s_ < SWIN);
            p = valid ? __expf(th) : 0.f;
          }
          lsum[j] += p;
          const int prow = wid * 16 + lq * 4 + j;
          const int pbyte = (prow << 7) + (((nt * 16 + lr) << 1) ^ ((prow & 7) << 4));
          *(bf16_t*)((char*)Ps + pbyte) = (bf16_t)p;
        }
      }

      // O += P V   (P rows wave-local: lgkmcnt handles, no barrier)
      __builtin_amdgcn_s_setprio(1);
#pragma unroll
      for (int ks = 0; ks < 2; ++ks) {
        const int prow = wid * 16 + lr;
        bf16x8 pf = *(const bf16x8*)((const char*)Ps + (prow << 7) +
                                     ((ks * 64 + hi * 16) ^ ((prow & 7) << 4)));
#pragma unroll
        for (int nt = 0; nt < 16; ++nt) {
          const int R = nt * 16 + lr;
          bf16x8 vf = *(const bf16x8*)((const char*)Vs + R * 128 +
                                       (((ks * 4 + hi) ^ (R & 7)) << 4));
          o[nt] = __builtin_amdgcn_mfma_f32_16x16x32_bf16(pf, vf, o[nt], 0, 0, 0);
        }
      }
      __builtin_amdgcn_s_setprio(0);
    }

    __syncthreads();  // all reads done before next tile's DMA overwrites
  }

#pragma unroll
  for (int j = 0; j < 4; ++j) {
    float l = lsum[j];
    l += __shfl_xor(l, 1);
    l += __shfl_xor(l, 2);
    l += __shfl_xor(l, 4);
    l += __shfl_xor(l, 8);
    const float inv = 1.f / l;
    const int t_ = trw + lq * 4 + j;
    bf16_t* op = AV + ((size_t)(b * SS + t_)) * (SNQ * SH) + head * SH;
#pragma unroll
    for (int nt = 0; nt < 16; ++nt) op[nt * 16 + lr] = (bf16_t)(o[nt][j] * inv);
  }
}

// ------------------------------------------------------------------- host
extern "C" void kernel_launch(void* const* d_in, const int* in_sizes, int n_in,
                              void* d_out, int out_size, void* d_ws, size_t ws_size,
                              hipStream_t stream) {
  const float* x = (const float*)d_in[0];
  const float* Wq = (const float*)d_in[1];
  const float* Wk = (const float*)d_in[2];
  const float* Wv = (const float*)d_in[3];
  const float* Wo = (const float*)d_in[4];
  float* out = (float*)d_out;

  char* ws = (char*)d_ws;
  size_t off = 0;
  auto alloc = [&](size_t elems) {
    bf16_t* p = (bf16_t*)(ws + off);
    off += ((elems * 2 + 255) & ~(size_t)255);
    return p;
  };
  const size_t MS = (size_t)SB * SS;        // 4096 rows
  bf16_t* xb    = alloc(MS * SD);                 // [4096][2048]
  bf16_t* wqT   = alloc((size_t)SNQ * SH * SD);   // [4096][2048]
  bf16_t* wkvT  = alloc((size_t)2 * SNKV * SH * SD); // K rows then V rows
  bf16_t* woT   = alloc((size_t)SD * SNQ * SH);   // [2048][4096]
  bf16_t* qb    = alloc(MS * SNQ * SH);           // [4096][4096]
  bf16_t* kvpre = alloc(MS * 2 * SNKV * SH);      // [4096][4096] K | V cols
  bf16_t* kb    = alloc(MS * SNKV * SH);          // [B][NKV][S][H]
  bf16_t* vt    = alloc(MS * SNKV * SH);          // [B][NKV][H][S]
  bf16_t* av    = alloc(MS * SNQ * SH);           // [4096][4096]
  (void)ws_size;  // ~218 MB

  cvt_kernel<<<(MS * SD / 4) / 256, 256, 0, stream>>>(x, xb);
  wtrans_kernel<<<dim3(SH / 64, SD / 64, 16), 256, 0, stream>>>(Wq, wqT, SD, SH);
  wtrans_kernel<<<dim3(SH / 64, SD / 64, 8), 256, 0, stream>>>(Wk, wkvT, SD, SH);
  wtrans_kernel<<<dim3(SH / 64, SD / 64, 8), 256, 0, stream>>>(Wv, wkvT + (size_t)SNKV * SH * SD, SD, SH);
  wtrans_kernel<<<dim3(SD / 64, (SNQ * SH) / 64, 1), 256, 0, stream>>>(Wo, woT, SNQ * SH, SD);

  gemm_bt<4, true><<<256, 512, 0, stream>>>(xb, wqT, qb, 4096, 4096, 2048);
  gemm_bt<4, true><<<256, 512, 0, stream>>>(xb, wkvT, kvpre, 4096, 4096, 2048);

  rope_k_kernel<<<(MS * SNKV * 16) / 256, 256, 0, stream>>>(kvpre, kb);
  vtrans_kernel<<<dim3(SH / 64, SS / 64, 16), 256, 0, stream>>>(kvpre + 2048, vt);

  attn_kernel<<<512, 512, 0, stream>>>(qb, kb, vt, av);

  gemm_bt<2, false><<<256, 512, 0, stream>>>(av, woT, out, 4096, 2048, 4096);
}

// Round 13
// 446.429 us; speedup vs baseline: 1.1296x; 1.0317x over previous
//
#include <hip/hip_runtime.h>
#include <stdint.h>

typedef __bf16 bf16_t;
typedef __bf16 bf16x8 __attribute__((ext_vector_type(8)));
typedef __bf16 bf16x4 __attribute__((ext_vector_type(4)));
typedef float f32x4 __attribute__((ext_vector_type(4)));

#define DEV static __device__ __forceinline__

// problem constants
#define SB 2
#define SS 2048
#define SD 2048
#define SNQ 16
#define SNKV 8
#define SH 256
#define SWIN 1024
#define QKVP 8192   // fused projection output pitch (Q | K | V)

DEV void async_ld16(const void* g, void* lds) {
  __builtin_amdgcn_global_load_lds(
      (const __attribute__((address_space(1))) void*)g,
      (__attribute__((address_space(3))) void*)lds, 16, 0, 0);
}

// ---------------------------------------------------------------- convert x
__global__ __launch_bounds__(256) void cvt_kernel(const float* __restrict__ in,
                                                  bf16_t* __restrict__ out) {
  int i = blockIdx.x * 256 + threadIdx.x;  // over n/4 elements
  float4 v = ((const float4*)in)[i];
  bf16x4 o = {(bf16_t)v.x, (bf16_t)v.y, (bf16_t)v.z, (bf16_t)v.w};
  *(bf16x4*)(out + (size_t)i * 4) = o;
}

// ------------------------------------------- batched transpose f32 -> bf16
// in [BZ][R][C] f32 -> out [BZ][C][R] bf16. 64x64 tiles, vector global
// access both directions (16B/lane), transpose via LDS (144B pitch + XOR).
__global__ __launch_bounds__(256) void wtrans_kernel(const float* __restrict__ in,
                                                     bf16_t* __restrict__ out,
                                                     int R, int C) {
  __shared__ bf16_t T[64 * 72];
  const int bz = blockIdx.z;
  const float* ip = in + (size_t)bz * R * C;
  bf16_t* op = out + (size_t)bz * R * C;
  const int r0 = blockIdx.y * 64, c0 = blockIdx.x * 64;
  const int tc = threadIdx.x & 15;        // 16 x 4 f32 = 64 cols
  const int tr = threadIdx.x >> 4;        // 0..15
#pragma unroll
  for (int i = 0; i < 4; ++i) {
    const int r = tr + i * 16;
    float4 v = *(const float4*)(ip + (size_t)(r0 + r) * C + c0 + tc * 4);
    float vv[4] = {v.x, v.y, v.z, v.w};
#pragma unroll
    for (int e = 0; e < 4; ++e) {
      const int row = tc * 4 + e;         // transposed row (= input col)
      *(bf16_t*)((char*)T + row * 144 + ((r * 2) ^ (((row >> 3) & 7) << 4))) =
          (bf16_t)vv[e];
    }
  }
  __syncthreads();
  const int tc2 = threadIdx.x & 7, tr2 = threadIdx.x >> 3;  // 0..31
#pragma unroll
  for (int i = 0; i < 2; ++i) {
    const int row = tr2 + i * 32;
    bf16x8 v = *(const bf16x8*)((const char*)T + row * 144 +
                                ((tc2 * 16) ^ (((row >> 3) & 7) << 4)));
    *(bf16x8*)(op + (size_t)(c0 + row) * R + r0 + tc2 * 8) = v;
  }
}

// ------------------------------------------------- V transpose bf16 -> bf16
// qkv [B*S][8192] (V cols start at 6144) -> vt [b*8+kv][H][S]. 64x64 tiles,
// vector global both directions, LDS transpose (144B pitch + XOR).
__global__ __launch_bounds__(256) void vtrans_kernel(const bf16_t* __restrict__ vbase,
                                                     bf16_t* __restrict__ vt) {
  __shared__ bf16_t T[64 * 72];
  const int bz = blockIdx.z, b = bz >> 3, kv = bz & 7;
  const int t0 = blockIdx.y * 64, h0 = blockIdx.x * 64;
  const int tc = threadIdx.x & 7, tr = threadIdx.x >> 3;  // tr 0..31
  const bf16_t* ip = vbase + (size_t)b * SS * QKVP + kv * SH;
#pragma unroll
  for (int i = 0; i < 2; ++i) {
    const int t = tr + i * 32;
    bf16x8 v = *(const bf16x8*)(ip + (size_t)(t0 + t) * QKVP + h0 + tc * 8);
#pragma unroll
    for (int e = 0; e < 8; ++e) {
      const int row = tc * 8 + e;         // h-row in transposed tile
      *(bf16_t*)((char*)T + row * 144 + ((t * 2) ^ (((row >> 3) & 7) << 4))) = v[e];
    }
  }
  __syncthreads();
  bf16_t* op = vt + (size_t)bz * SH * SS;
#pragma unroll
  for (int i = 0; i < 2; ++i) {
    const int row = tr + i * 32;
    bf16x8 v = *(const bf16x8*)((const char*)T + row * 144 +
                                ((tc * 16) ^ (((row >> 3) & 7) << 4)));
    *(bf16x8*)(op + (size_t)(h0 + row) * SS + t0 + tc * 8) = v;
  }
}

// --------------------------------------------------------- RoPE-K (vector)
// qkv [B*S][8192] (K cols 4096..6143) -> kb [B][NKV][S][H] with rope.
__global__ __launch_bounds__(256) void rope_k_kernel(const bf16_t* __restrict__ qkv,
                                                     bf16_t* __restrict__ kb) {
  int idx = blockIdx.x * 256 + threadIdx.x;      // B*S*NKV*16
  const int i8 = (idx & 15) << 3;                // 0..120
  const int kv = (idx >> 4) & 7;
  const int row = idx >> 7;                      // 0..4095
  const int t = row & (SS - 1), b = row >> 11;
  const size_t ib = (size_t)row * QKVP + 4096 + kv * SH;
  bf16x8 x1 = *(const bf16x8*)(qkv + ib + i8);
  bf16x8 x2 = *(const bf16x8*)(qkv + ib + i8 + 128);
  bf16x8 r1, r2;
#pragma unroll
  for (int e = 0; e < 8; ++e) {
    float c_ = (float)(i8 + e);
    float inv = __expf(c_ * -0.07195578f);       // ln(10000)/128
    float fr = (float)t * inv;
    float cs = __cosf(fr), sn = __sinf(fr);
    float a = (float)x1[e], b2 = (float)x2[e];
    r1[e] = (bf16_t)(a * cs - b2 * sn);
    r2[e] = (bf16_t)(b2 * cs + a * sn);
  }
  const size_t ob = ((size_t)(b * SNKV + kv) * SS + t) * SH;
  *(bf16x8*)(kb + ob + i8) = r1;
  *(bf16x8*)(kb + ob + i8 + 128) = r2;
}

// ------------------------------------------------------------------- GEMM
// C[M][N] = A[M][K] * Bt[N][K]^T ; 256 x (NBW*64) tile, BK=32, 8 waves.
// 4-deep LDS ring, counted vmcnt (T4), setprio around MFMA (T5).
template <int NBW, bool OUT_BF16>
__global__ __launch_bounds__(512, 2) void gemm_bt(const bf16_t* __restrict__ A,
                                                  const bf16_t* __restrict__ Bt,
                                                  void* __restrict__ Cout,
                                                  int M, int N, int K) {
  constexpr int BN = NBW * 64;
  constexpr int MFR = (256 / (8 / NBW)) / 16;   // m-frags per wave (8 or 4)
  constexpr int ALOADS = 2;
  constexpr int BLOADS = NBW / 2;
  constexpr int LT = ALOADS + BLOADS;
  __shared__ bf16_t As[4][256 * 32];
  __shared__ bf16_t Bs[4][BN * 32];

  const int tid = threadIdx.x, lane = tid & 63, wid = tid >> 6;
  const int nbx = N / BN;
  const int nwg = (M >> 8) * nbx;
  const int cpx = nwg >> 3;
  const int lb = (blockIdx.x & 7) * cpx + (blockIdx.x >> 3);  // XCD chunking
  const int bx = lb % nbx, by = lb / nbx;
  const int row0 = by << 8;
  const int col0 = bx * BN;
  const int wr = wid / NBW, wc = wid % NBW;
  const int lr = lane & 15, hi = lane >> 4;

  const bf16_t* Arow = A + (size_t)row0 * K;
  const bf16_t* Brow = Bt + (size_t)col0 * K;

  auto stageA = [&](int t) {
    const int k0 = t << 5;
#pragma unroll
    for (int it = 0; it < ALOADS; ++it) {
      const int f = tid + (it << 9);
      async_ld16(Arow + (size_t)(f >> 2) * K + k0 + ((f & 3) << 3),
                 (char*)As[t & 3] + f * 16);
    }
  };
  auto stageB = [&](int t) {
    const int k0 = t << 5;
#pragma unroll
    for (int it = 0; it < BLOADS; ++it) {
      const int f = tid + (it << 9);
      async_ld16(Brow + (size_t)(f >> 2) * K + k0 + ((f & 3) << 3),
                 (char*)Bs[t & 3] + f * 16);
    }
  };

  f32x4 acc[MFR][4];
#pragma unroll
  for (int m = 0; m < MFR; ++m)
#pragma unroll
    for (int n = 0; n < 4; ++n) acc[m][n] = f32x4{0.f, 0.f, 0.f, 0.f};

  const int NT = K >> 5;
  stageA(0); stageB(0); stageA(1); stageB(1); stageA(2); stageB(2);
  asm volatile("s_waitcnt vmcnt(%0)" ::"i"(2 * LT) : "memory");
  __builtin_amdgcn_s_barrier();
  __builtin_amdgcn_sched_barrier(0);

  for (int t = 0; t < NT; ++t) {
    const bf16_t* Ab = &As[t & 3][(wr * (MFR * 16)) * 32];
    const bf16_t* Bb = &Bs[t & 3][(wc * 64) * 32];
    const bool pre = (t + 3 < NT);

    bf16x8 bfr[4];
#pragma unroll
    for (int nf = 0; nf < 4; ++nf)
      bfr[nf] = *(const bf16x8*)&Bb[(nf * 16 + lr) * 32 + hi * 8];

#pragma unroll
    for (int ph = 0; ph < MFR / 4; ++ph) {
      if (pre && ph == 0) stageA(t + 3);
      if (pre && ph == (MFR / 4) - 1) stageB(t + 3);
      bf16x8 af[4];
#pragma unroll
      for (int mf = 0; mf < 4; ++mf)
        af[mf] = *(const bf16x8*)&Ab[((ph * 4 + mf) * 16 + lr) * 32 + hi * 8];
      __builtin_amdgcn_s_setprio(1);
#pragma unroll
      for (int mf = 0; mf < 4; ++mf)
#pragma unroll
        for (int nf = 0; nf < 4; ++nf)
          acc[ph * 4 + mf][nf] = __builtin_amdgcn_mfma_f32_16x16x32_bf16(
              af[mf], bfr[nf], acc[ph * 4 + mf][nf], 0, 0, 0);
      __builtin_amdgcn_s_setprio(0);
    }

    if (t + 3 < NT) {
      asm volatile("s_waitcnt vmcnt(%0)" ::"i"(2 * LT) : "memory");
    } else if (t + 2 < NT) {
      asm volatile("s_waitcnt vmcnt(%0)" ::"i"(LT) : "memory");
    } else if (t + 1 < NT) {
      asm volatile("s_waitcnt vmcnt(0)" ::: "memory");
    }
    if (t + 1 < NT) {
      __builtin_amdgcn_s_barrier();
      __builtin_amdgcn_sched_barrier(0);
    }
  }

#pragma unroll
  for (int mf = 0; mf < MFR; ++mf) {
    const int r = row0 + wr * (MFR * 16) + mf * 16 + hi * 4;
#pragma unroll
    for (int nf = 0; nf < 4; ++nf) {
      const int c = col0 + wc * 64 + nf * 16 + lr;
#pragma unroll
      for (int j = 0; j < 4; ++j) {
        if (OUT_BF16)
          ((bf16_t*)Cout)[(size_t)(r + j) * N + c] = (bf16_t)acc[mf][nf][j];
        else
          ((float*)Cout)[(size_t)(r + j) * N + c] = acc[mf][nf][j];
      }
    }
  }
}

// -------------------------------------------------------------- attention
// R7 kernel verbatim (best measured: 123 us), Q pitch adjusted to the fused
// QKV buffer. Per block: (b, head, 128 q rows), 8 waves x 16 q rows each.
// KVB=64 double-buffer, RoPE-Q fused into the Q register load, fixed-base
// softmax (softcap bounds logits to +-50 -> no online max / rescale).
// LPT dispatch: heavy q-tiles decode from LOW bid; XCD x owns kvh=x.
// Swizzles (both-sides XOR involutions): K/V chunk ^= (row & 7).
#define QB 128
#define KVB 64
#define PP 72    // Ps pitch 144B

__global__ __launch_bounds__(512, 2) void attn_kernel(
    const bf16_t* __restrict__ Q,   // [B*S][QKVP] (RAW fused projection)
    const bf16_t* __restrict__ Kt,  // [B][NKV][S][H] (roped)
    const bf16_t* __restrict__ Vt,  // [B][NKV][H][S]
    bf16_t* __restrict__ AV) {      // [B*S][NQ*H]
  __shared__ bf16_t Ks[2][KVB * SH];   // 2 x 32 KB, row pitch 512B
  __shared__ bf16_t Vs[2][SH * KVB];   // 2 x 32 KB, row pitch 128B
  __shared__ bf16_t Ps[QB * PP];       // 18 KB

  const int tid = threadIdx.x, lane = tid & 63, wid = tid >> 6;
  // LPT + XCD-locality decode
  const int x = blockIdx.x & 7;
  const int y = blockIdx.x >> 3;       // 0..63
  const int qt = 15 - (y & 15);        // heavy tiles dispatch first
  const int head = (x << 1) | ((y >> 4) & 1);
  const int b = y >> 5;
  const int kvh = x;
  const int t0 = qt << 7;
  const int trw = t0 + wid * 16;       // this wave's first q row
  const int lr = lane & 15, hi = lane >> 4;
  const int lk = hi << 3;
  const int lq = hi;

  // Q load + fused RoPE + 1/16 scale (pair (c, c+128) = qf[ks], qf[ks+4])
  bf16x8 qf[8];
  {
    const bf16_t* qp = Q + ((size_t)(b * SS + trw + lr)) * QKVP + head * SH + lk;
#pragma unroll
    for (int ks = 0; ks < 8; ++ks) qf[ks] = *(const bf16x8*)(qp + ks * 32);
    const float tpos = (float)(trw + lr);
#pragma unroll
    for (int ks = 0; ks < 4; ++ks) {
      bf16x8 a = qf[ks], b2 = qf[ks + 4];
      bf16x8 ra, rb;
#pragma unroll
      for (int e = 0; e < 8; ++e) {
        float c_ = (float)(ks * 32 + lk + e);
        float inv = __expf(c_ * -0.07195578f);
        float fr = tpos * inv;
        float cs = __cosf(fr), sn = __sinf(fr);
        float x1 = (float)a[e], x2 = (float)b2[e];
        ra[e] = (bf16_t)((x1 * cs - x2 * sn) * 0.0625f);
        rb[e] = (bf16_t)((x2 * cs + x1 * sn) * 0.0625f);
      }
      qf[ks] = ra; qf[ks + 4] = rb;
    }
  }

  f32x4 o[16];
#pragma unroll
  for (int i = 0; i < 16; ++i) o[i] = f32x4{0.f, 0.f, 0.f, 0.f};
  float lsum[4] = {0.f, 0.f, 0.f, 0.f};

  const bf16_t* Kb = Kt + (size_t)(b * SNKV + kvh) * SS * SH;
  const bf16_t* Vb = Vt + (size_t)(b * SNKV + kvh) * SH * SS;

  const int sv0 = (t0 >= SWIN) ? ((t0 >> 6) - 16) : 0;
  const int sv1 = (t0 >> 6) + 1;

  // DMA-stage K (64x256) + V^T (256x64) into buf d; both-sides XOR swizzle.
  auto stage = [&](int s0, int d) {
#pragma unroll
    for (int it = 0; it < 4; ++it) {
      const int f = tid + (it << 9);           // 0..2047
      {
        const int r = f >> 5, pc = f & 31;
        const int sc = pc ^ (r & 7);
        async_ld16(Kb + (size_t)(s0 + r) * SH + sc * 8, (char*)Ks[d] + f * 16);
      }
      {
        const int r = f >> 3, pc = f & 7;
        const int sc = pc ^ (r & 7);
        async_ld16(Vb + (size_t)r * SS + s0 + sc * 8, (char*)Vs[d] + f * 16);
      }
    }
  };

  stage(sv0 << 6, 0);
  __syncthreads();

  int cur = 0;
  for (int sv = sv0; sv <= sv1; ++sv, cur ^= 1) {
    if (sv < sv1) stage((sv + 1) << 6, cur ^ 1);

    const int s0 = sv << 6;
    const bool skip = (s0 > trw + 15) || (s0 + 63 < trw - (SWIN - 1));
    if (!skip) {
      const bf16_t* Kc = Ks[cur];
      const bf16_t* Vc = Vs[cur];
      // S = Q K^T (4 col-frags of 16)
      f32x4 sacc[4];
#pragma unroll
      for (int nt = 0; nt < 4; ++nt) sacc[nt] = f32x4{0.f, 0.f, 0.f, 0.f};
      __builtin_amdgcn_s_setprio(1);
#pragma unroll
      for (int ks = 0; ks < 8; ++ks) {
#pragma unroll
        for (int nt = 0; nt < 4; ++nt) {
          const int R = nt * 16 + lr;
          bf16x8 kf = *(const bf16x8*)((const char*)Kc + R * 512 +
                                       (((ks * 4 + hi) ^ (R & 7)) << 4));
          sacc[nt] = __builtin_amdgcn_mfma_f32_16x16x32_bf16(qf[ks], kf, sacc[nt], 0, 0, 0);
        }
      }
      __builtin_amdgcn_s_setprio(0);

      // softcap + exp (fixed base), write P
      const bool full = (s0 + 63 <= trw) && (s0 >= trw + 15 - (SWIN - 1));
      if (full) {
#pragma unroll
        for (int nt = 0; nt < 4; ++nt) {
#pragma unroll
          for (int j = 0; j < 4; ++j) {
            float u = sacc[nt][j] * 0.04f;
            float th = 50.f - 100.f * __builtin_amdgcn_rcpf(__expf(u) + 1.f);
            float p = __expf(th);
            lsum[j] += p;
            Ps[(wid * 16 + lq * 4 + j) * PP + nt * 16 + lr] = (bf16_t)p;
          }
        }
      } else {
#pragma unroll
        for (int nt = 0; nt < 4; ++nt) {
          const int s_ = s0 + nt * 16 + lr;
#pragma unroll
          for (int j = 0; j < 4; ++j) {
            const int t_ = trw + lq * 4 + j;
            float u = sacc[nt][j] * 0.04f;
            float th = 50.f - 100.f * __builtin_amdgcn_rcpf(__expf(u) + 1.f);
            const bool valid = (s_ <= t_) && (t_ - s_ < SWIN);
            float p = valid ? __expf(th) : 0.f;
            lsum[j] += p;
            Ps[(wid * 16 + lq * 4 + j) * PP + nt * 16 + lr] = (bf16_t)p;
          }
        }
      }

      // O += P V   (P rows wave-local: no barrier needed)
      __builtin_amdgcn_s_setprio(1);
#pragma unroll
      for (int ks = 0; ks < 2; ++ks) {
        bf16x8 pf = *(const bf16x8*)&Ps[(wid * 16 + lr) * PP + ks * 32 + lk];
#pragma unroll
        for (int nt = 0; nt < 16; ++nt) {
          const int R = nt * 16 + lr;
          bf16x8 vf = *(const bf16x8*)((const char*)Vc + R * 128 +
                                       (((ks * 4 + hi) ^ (R & 7)) << 4));
          o[nt] = __builtin_amdgcn_mfma_f32_16x16x32_bf16(pf, vf, o[nt], 0, 0, 0);
        }
      }
      __builtin_amdgcn_s_setprio(0);
    }

    __syncthreads();
  }

#pragma unroll
  for (int j = 0; j < 4; ++j) {
    float l = lsum[j];
    l += __shfl_xor(l, 1);
    l += __shfl_xor(l, 2);
    l += __shfl_xor(l, 4);
    l += __shfl_xor(l, 8);
    const float inv = 1.f / l;
    const int t_ = trw + lq * 4 + j;
    bf16_t* op = AV + ((size_t)(b * SS + t_)) * (SNQ * SH) + head * SH;
#pragma unroll
    for (int nt = 0; nt < 16; ++nt) op[nt * 16 + lr] = (bf16_t)(o[nt][j] * inv);
  }
}

// ------------------------------------------------------------------- host
extern "C" void kernel_launch(void* const* d_in, const int* in_sizes, int n_in,
                              void* d_out, int out_size, void* d_ws, size_t ws_size,
                              hipStream_t stream) {
  const float* x = (const float*)d_in[0];
  const float* Wq = (const float*)d_in[1];
  const float* Wk = (const float*)d_in[2];
  const float* Wv = (const float*)d_in[3];
  const float* Wo = (const float*)d_in[4];
  float* out = (float*)d_out;

  char* ws = (char*)d_ws;
  size_t off = 0;
  auto alloc = [&](size_t elems) {
    bf16_t* p = (bf16_t*)(ws + off);
    off += ((elems * 2 + 255) & ~(size_t)255);
    return p;
  };
  const size_t MS = (size_t)SB * SS;        // 4096 rows
  bf16_t* xb     = alloc(MS * SD);                 // [4096][2048]
  bf16_t* wqkvT  = alloc((size_t)QKVP * SD);       // [8192][2048]: Wq|Wk|Wv rows
  bf16_t* woT    = alloc((size_t)SD * SNQ * SH);   // [2048][4096]
  bf16_t* qkv    = alloc(MS * QKVP);               // [4096][8192]: Q|K|V cols
  bf16_t* kb     = alloc(MS * SNKV * SH);          // [B][NKV][S][H]
  bf16_t* vt     = alloc(MS * SNKV * SH);          // [B][NKV][H][S]
  bf16_t* av     = alloc(MS * SNQ * SH);           // [4096][4096]
  (void)ws_size;  // ~178 MB

  cvt_kernel<<<(MS * SD / 4) / 256, 256, 0, stream>>>(x, xb);
  // weight transposes into the fused Bt: rows 0..4095 = Wq^T heads,
  // 4096..6143 = Wk^T, 6144..8191 = Wv^T
  wtrans_kernel<<<dim3(SH / 64, SD / 64, 16), 256, 0, stream>>>(Wq, wqkvT, SD, SH);
  wtrans_kernel<<<dim3(SH / 64, SD / 64, 8), 256, 0, stream>>>(Wk, wqkvT + (size_t)4096 * SD, SD, SH);
  wtrans_kernel<<<dim3(SH / 64, SD / 64, 8), 256, 0, stream>>>(Wv, wqkvT + (size_t)6144 * SD, SD, SH);
  wtrans_kernel<<<dim3(SD / 64, (SNQ * SH) / 64, 1), 256, 0, stream>>>(Wo, woT, SNQ * SH, SD);

  // fused Q|K|V projection: [4096x2048] x [8192x2048]^T -> [4096][8192]
  gemm_bt<4, true><<<512, 512, 0, stream>>>(xb, wqkvT, qkv, 4096, QKVP, 2048);

  rope_k_kernel<<<(MS * SNKV * 16) / 256, 256, 0, stream>>>(qkv, kb);
  vtrans_kernel<<<dim3(SH / 64, SS / 64, 16), 256, 0, stream>>>(qkv + 6144, vt);

  attn_kernel<<<512, 512, 0, stream>>>(qkv, kb, vt, av);

  gemm_bt<2, false><<<256, 512, 0, stream>>>(av, woT, out, 4096, 2048, 4096);
}

// Round 14
// 392.088 us; speedup vs baseline: 1.2862x; 1.1386x over previous
//
#include <hip/hip_runtime.h>
#include <stdint.h>

typedef __bf16 bf16_t;
typedef __bf16 bf16x8 __attribute__((ext_vector_type(8)));
typedef __bf16 bf16x4 __attribute__((ext_vector_type(4)));
typedef float f32x4 __attribute__((ext_vector_type(4)));

#define DEV static __device__ __forceinline__

// problem constants
#define SB 2
#define SS 2048
#define SD 2048
#define SNQ 16
#define SNKV 8
#define SH 256
#define SWIN 1024
#define QKVP 8192   // fused projection output pitch (Q | K | V)

DEV void async_ld16(const void* g, void* lds) {
  __builtin_amdgcn_global_load_lds(
      (const __attribute__((address_space(1))) void*)g,
      (__attribute__((address_space(3))) void*)lds, 16, 0, 0);
}

// ---------------------------------------------------------------- convert x
__global__ __launch_bounds__(256) void cvt_kernel(const float* __restrict__ in,
                                                  bf16_t* __restrict__ out) {
  int i = blockIdx.x * 256 + threadIdx.x;  // over n/4 elements
  float4 v = ((const float4*)in)[i];
  bf16x4 o = {(bf16_t)v.x, (bf16_t)v.y, (bf16_t)v.z, (bf16_t)v.w};
  *(bf16x4*)(out + (size_t)i * 4) = o;
}

// ------------------------------------------- batched transpose f32 -> bf16
// 64x64 tiles, vector global both directions, LDS transpose (144B pitch+XOR).
__global__ __launch_bounds__(256) void wtrans_kernel(const float* __restrict__ in,
                                                     bf16_t* __restrict__ out,
                                                     int R, int C) {
  __shared__ bf16_t T[64 * 72];
  const int bz = blockIdx.z;
  const float* ip = in + (size_t)bz * R * C;
  bf16_t* op = out + (size_t)bz * R * C;
  const int r0 = blockIdx.y * 64, c0 = blockIdx.x * 64;
  const int tc = threadIdx.x & 15;        // 16 x 4 f32 = 64 cols
  const int tr = threadIdx.x >> 4;        // 0..15
#pragma unroll
  for (int i = 0; i < 4; ++i) {
    const int r = tr + i * 16;
    float4 v = *(const float4*)(ip + (size_t)(r0 + r) * C + c0 + tc * 4);
    float vv[4] = {v.x, v.y, v.z, v.w};
#pragma unroll
    for (int e = 0; e < 4; ++e) {
      const int row = tc * 4 + e;         // transposed row (= input col)
      *(bf16_t*)((char*)T + row * 144 + ((r * 2) ^ (((row >> 3) & 7) << 4))) =
          (bf16_t)vv[e];
    }
  }
  __syncthreads();
  const int tc2 = threadIdx.x & 7, tr2 = threadIdx.x >> 3;  // 0..31
#pragma unroll
  for (int i = 0; i < 2; ++i) {
    const int row = tr2 + i * 32;
    bf16x8 v = *(const bf16x8*)((const char*)T + row * 144 +
                                ((tc2 * 16) ^ (((row >> 3) & 7) << 4)));
    *(bf16x8*)(op + (size_t)(c0 + row) * R + r0 + tc2 * 8) = v;
  }
}

// ------------------------------------------------- V transpose bf16 -> bf16
// qkv [B*S][8192] (V cols start at 6144) -> vt [b*8+kv][H][S].
__global__ __launch_bounds__(256) void vtrans_kernel(const bf16_t* __restrict__ vbase,
                                                     bf16_t* __restrict__ vt) {
  __shared__ bf16_t T[64 * 72];
  const int bz = blockIdx.z, b = bz >> 3, kv = bz & 7;
  const int t0 = blockIdx.y * 64, h0 = blockIdx.x * 64;
  const int tc = threadIdx.x & 7, tr = threadIdx.x >> 3;  // tr 0..31
  const bf16_t* ip = vbase + (size_t)b * SS * QKVP + kv * SH;
#pragma unroll
  for (int i = 0; i < 2; ++i) {
    const int t = tr + i * 32;
    bf16x8 v = *(const bf16x8*)(ip + (size_t)(t0 + t) * QKVP + h0 + tc * 8);
#pragma unroll
    for (int e = 0; e < 8; ++e) {
      const int row = tc * 8 + e;         // h-row in transposed tile
      *(bf16_t*)((char*)T + row * 144 + ((t * 2) ^ (((row >> 3) & 7) << 4))) = v[e];
    }
  }
  __syncthreads();
  bf16_t* op = vt + (size_t)bz * SH * SS;
#pragma unroll
  for (int i = 0; i < 2; ++i) {
    const int row = tr + i * 32;
    bf16x8 v = *(const bf16x8*)((const char*)T + row * 144 +
                                ((tc * 16) ^ (((row >> 3) & 7) << 4)));
    *(bf16x8*)(op + (size_t)(h0 + row) * SS + t0 + tc * 8) = v;
  }
}

// --------------------------------------------------------- RoPE-K (vector)
// qkv [B*S][8192] (K cols 4096..6143) -> kb [B][NKV][S][H] with rope.
__global__ __launch_bounds__(256) void rope_k_kernel(const bf16_t* __restrict__ qkv,
                                                     bf16_t* __restrict__ kb) {
  int idx = blockIdx.x * 256 + threadIdx.x;      // B*S*NKV*16
  const int i8 = (idx & 15) << 3;                // 0..120
  const int kv = (idx >> 4) & 7;
  const int row = idx >> 7;                      // 0..4095
  const int t = row & (SS - 1), b = row >> 11;
  const size_t ib = (size_t)row * QKVP + 4096 + kv * SH;
  bf16x8 x1 = *(const bf16x8*)(qkv + ib + i8);
  bf16x8 x2 = *(const bf16x8*)(qkv + ib + i8 + 128);
  bf16x8 r1, r2;
#pragma unroll
  for (int e = 0; e < 8; ++e) {
    float c_ = (float)(i8 + e);
    float inv = __expf(c_ * -0.07195578f);       // ln(10000)/128
    float fr = (float)t * inv;
    float cs = __cosf(fr), sn = __sinf(fr);
    float a = (float)x1[e], b2 = (float)x2[e];
    r1[e] = (bf16_t)(a * cs - b2 * sn);
    r2[e] = (bf16_t)(b2 * cs + a * sn);
  }
  const size_t ob = ((size_t)(b * SNKV + kv) * SS + t) * SH;
  *(bf16x8*)(kb + ob + i8) = r1;
  *(bf16x8*)(kb + ob + i8 + 128) = r2;
}

// ------------------------------------------------- GEMM (ring, for O-proj)
template <int NBW, bool OUT_BF16>
__global__ __launch_bounds__(512, 2) void gemm_bt(const bf16_t* __restrict__ A,
                                                  const bf16_t* __restrict__ Bt,
                                                  void* __restrict__ Cout,
                                                  int M, int N, int K) {
  constexpr int BN = NBW * 64;
  constexpr int MFR = (256 / (8 / NBW)) / 16;
  constexpr int ALOADS = 2;
  constexpr int BLOADS = NBW / 2;
  constexpr int LT = ALOADS + BLOADS;
  __shared__ bf16_t As[4][256 * 32];
  __shared__ bf16_t Bs[4][BN * 32];

  const int tid = threadIdx.x, lane = tid & 63, wid = tid >> 6;
  const int nbx = N / BN;
  const int nwg = (M >> 8) * nbx;
  const int cpx = nwg >> 3;
  const int lb = (blockIdx.x & 7) * cpx + (blockIdx.x >> 3);
  const int bx = lb % nbx, by = lb / nbx;
  const int row0 = by << 8;
  const int col0 = bx * BN;
  const int wr = wid / NBW, wc = wid % NBW;
  const int lr = lane & 15, hi = lane >> 4;

  const bf16_t* Arow = A + (size_t)row0 * K;
  const bf16_t* Brow = Bt + (size_t)col0 * K;

  auto stageA = [&](int t) {
    const int k0 = t << 5;
#pragma unroll
    for (int it = 0; it < ALOADS; ++it) {
      const int f = tid + (it << 9);
      async_ld16(Arow + (size_t)(f >> 2) * K + k0 + ((f & 3) << 3),
                 (char*)As[t & 3] + f * 16);
    }
  };
  auto stageB = [&](int t) {
    const int k0 = t << 5;
#pragma unroll
    for (int it = 0; it < BLOADS; ++it) {
      const int f = tid + (it << 9);
      async_ld16(Brow + (size_t)(f >> 2) * K + k0 + ((f & 3) << 3),
                 (char*)Bs[t & 3] + f * 16);
    }
  };

  f32x4 acc[MFR][4];
#pragma unroll
  for (int m = 0; m < MFR; ++m)
#pragma unroll
    for (int n = 0; n < 4; ++n) acc[m][n] = f32x4{0.f, 0.f, 0.f, 0.f};

  const int NT = K >> 5;
  stageA(0); stageB(0); stageA(1); stageB(1); stageA(2); stageB(2);
  asm volatile("s_waitcnt vmcnt(%0)" ::"i"(2 * LT) : "memory");
  __builtin_amdgcn_s_barrier();
  __builtin_amdgcn_sched_barrier(0);

  for (int t = 0; t < NT; ++t) {
    const bf16_t* Ab = &As[t & 3][(wr * (MFR * 16)) * 32];
    const bf16_t* Bb = &Bs[t & 3][(wc * 64) * 32];
    const bool pre = (t + 3 < NT);

    bf16x8 bfr[4];
#pragma unroll
    for (int nf = 0; nf < 4; ++nf)
      bfr[nf] = *(const bf16x8*)&Bb[(nf * 16 + lr) * 32 + hi * 8];

#pragma unroll
    for (int ph = 0; ph < MFR / 4; ++ph) {
      if (pre && ph == 0) stageA(t + 3);
      if (pre && ph == (MFR / 4) - 1) stageB(t + 3);
      bf16x8 af[4];
#pragma unroll
      for (int mf = 0; mf < 4; ++mf)
        af[mf] = *(const bf16x8*)&Ab[((ph * 4 + mf) * 16 + lr) * 32 + hi * 8];
      __builtin_amdgcn_s_setprio(1);
#pragma unroll
      for (int mf = 0; mf < 4; ++mf)
#pragma unroll
        for (int nf = 0; nf < 4; ++nf)
          acc[ph * 4 + mf][nf] = __builtin_amdgcn_mfma_f32_16x16x32_bf16(
              af[mf], bfr[nf], acc[ph * 4 + mf][nf], 0, 0, 0);
      __builtin_amdgcn_s_setprio(0);
    }

    if (t + 3 < NT) {
      asm volatile("s_waitcnt vmcnt(%0)" ::"i"(2 * LT) : "memory");
    } else if (t + 2 < NT) {
      asm volatile("s_waitcnt vmcnt(%0)" ::"i"(LT) : "memory");
    } else if (t + 1 < NT) {
      asm volatile("s_waitcnt vmcnt(0)" ::: "memory");
    }
    if (t + 1 < NT) {
      __builtin_amdgcn_s_barrier();
      __builtin_amdgcn_sched_barrier(0);
    }
  }

#pragma unroll
  for (int mf = 0; mf < MFR; ++mf) {
    const int r = row0 + wr * (MFR * 16) + mf * 16 + hi * 4;
#pragma unroll
    for (int nf = 0; nf < 4; ++nf) {
      const int c = col0 + wc * 64 + nf * 16 + lr;
#pragma unroll
      for (int j = 0; j < 4; ++j) {
        if (OUT_BF16)
          ((bf16_t*)Cout)[(size_t)(r + j) * N + c] = (bf16_t)acc[mf][nf][j];
        else
          ((float*)Cout)[(size_t)(r + j) * N + c] = acc[mf][nf][j];
      }
    }
  }
}

// ---------------------------------------- GEMM 8-phase (QKV projection)
// 256x256 tile, BK=64, 8 waves (2Mx4N), 2-deep LDS dbuf (128 KB).
// Interleaved frag layout: phase q touches only A rows 64q..64q+63, so
// staging {Bh0,Bh1,Ah0,Ah1}(t+1) at phases 0-3 allows COUNTED vmcnt:
//   vmcnt(4) before ph1-end barrier  (Ah1(t) landed for ph2/ph3 reads)
//   vmcnt(2) before ph3-end barrier  (Bh0,Bh1,Ah0(t+1) landed for ph0/ph1)
// -> never drain to 0; <=3 half-tiles in flight across barriers (T4).
// LDS swizzle (both sides): slot ^= (row & 7) at 128B row pitch (T2).
// Grid hardcoded 16x32 blocks; each XCD owns an 8x8 (by,bx) square
// (A 8MB + B 8MB footprint -> L2-friendly, FETCH ~halved).
__global__ __launch_bounds__(512, 1) void gemm8p(const bf16_t* __restrict__ A,
                                                 const bf16_t* __restrict__ Bt,
                                                 bf16_t* __restrict__ C,
                                                 int M, int N, int K) {
  __shared__ bf16_t As[2][256 * 64];   // 2 x 32 KB
  __shared__ bf16_t Bs[2][256 * 64];   // 2 x 32 KB

  const int tid = threadIdx.x, lane = tid & 63, wid = tid >> 6;
  // XCD-square decode (grid = 16 by x 32 bx = 512 blocks)
  const int xcd = blockIdx.x & 7, ii = blockIdx.x >> 3;   // ii 0..63
  const int by = (xcd & 1) * 8 + (ii >> 3);
  const int bx = (xcd >> 1) * 8 + (ii & 7);
  const int row0 = by << 8, col0 = bx << 8;
  const int wr = wid >> 2, wc = wid & 3;   // 2 x 4 waves
  const int lr = lane & 15, hi = lane >> 4;

  const bf16_t* Arow = A + (size_t)row0 * K;
  const bf16_t* Brow = Bt + (size_t)col0 * K;

  // stage one 16KB half-tile (128 rows x 64 cols) of tile t, half h.
  // dest linear f*16; source col pre-swizzled: sc = pc ^ (r&7).
  auto stageHA = [&](int t, int h) {
#pragma unroll
    for (int i = 0; i < 2; ++i) {
      const int f = tid + (i << 9);
      const int r = (h << 7) + (f >> 3), pc = f & 7;
      async_ld16(Arow + (size_t)r * K + (t << 6) + (pc ^ (r & 7)) * 8,
                 (char*)As[t & 1] + (h << 14) + f * 16);
    }
  };
  auto stageHB = [&](int t, int h) {
#pragma unroll
    for (int i = 0; i < 2; ++i) {
      const int f = tid + (i << 9);
      const int r = (h << 7) + (f >> 3), pc = f & 7;
      async_ld16(Brow + (size_t)r * K + (t << 6) + (pc ^ (r & 7)) * 8,
                 (char*)Bs[t & 1] + (h << 14) + f * 16);
    }
  };

  f32x4 acc[8][4];
#pragma unroll
  for (int m = 0; m < 8; ++m)
#pragma unroll
    for (int n = 0; n < 4; ++n) acc[m][n] = f32x4{0.f, 0.f, 0.f, 0.f};

  const int NT = K >> 6;
  // prologue: stage tile 0 fully; need first 3 halves -> vmcnt(2)
  stageHB(0, 0); stageHB(0, 1); stageHA(0, 0); stageHA(0, 1);
  asm volatile("s_waitcnt vmcnt(2)" ::: "memory");
  __builtin_amdgcn_s_barrier();
  __builtin_amdgcn_sched_barrier(0);

  for (int t = 0; t < NT; ++t) {
    const bool pre = (t + 1 < NT);
    const char* Ab = (const char*)As[t & 1];
    const char* Bb = (const char*)Bs[t & 1];
    bf16x8 bfr[4][2];

#pragma unroll
    for (int q = 0; q < 4; ++q) {
      // ds_read this phase's register subtile
      if (q == 0) {
#pragma unroll
        for (int nf = 0; nf < 4; ++nf)
#pragma unroll
          for (int ks = 0; ks < 2; ++ks) {
            const int r = nf * 64 + wc * 16 + lr;
            bfr[nf][ks] = *(const bf16x8*)(Bb + r * 128 +
                                           ((((ks << 2) + hi) ^ (r & 7)) << 4));
          }
      }
      bf16x8 af[2][2];
#pragma unroll
      for (int mq = 0; mq < 2; ++mq)
#pragma unroll
        for (int ks = 0; ks < 2; ++ks) {
          const int r = q * 64 + mq * 32 + wr * 16 + lr;
          af[mq][ks] = *(const bf16x8*)(Ab + r * 128 +
                                        ((((ks << 2) + hi) ^ (r & 7)) << 4));
        }
      // issue next tile's half-tile stage (1 per phase)
      if (pre) {
        if (q == 0) stageHB(t + 1, 0);
        if (q == 1) stageHB(t + 1, 1);
        if (q == 2) stageHA(t + 1, 0);
        if (q == 3) stageHA(t + 1, 1);
      }
      asm volatile("s_waitcnt lgkmcnt(0)" ::: "memory");
      __builtin_amdgcn_sched_barrier(0);
      __builtin_amdgcn_s_setprio(1);
#pragma unroll
      for (int mq = 0; mq < 2; ++mq)
#pragma unroll
        for (int nf = 0; nf < 4; ++nf)
#pragma unroll
          for (int ks = 0; ks < 2; ++ks)
            acc[q * 2 + mq][nf] = __builtin_amdgcn_mfma_f32_16x16x32_bf16(
                af[mq][ks], bfr[nf][ks], acc[q * 2 + mq][nf], 0, 0, 0);
      __builtin_amdgcn_s_setprio(0);
      // counted waits BEFORE the barrier (producer observation -> barrier
      // -> consumer read ordering)
      if (q == 1) {
        if (pre) asm volatile("s_waitcnt vmcnt(4)" ::: "memory");
        else     asm volatile("s_waitcnt vmcnt(0)" ::: "memory");
      }
      if (q == 3 && pre) asm volatile("s_waitcnt vmcnt(2)" ::: "memory");
      if (!(q == 3 && !pre)) {
        __builtin_amdgcn_s_barrier();
        __builtin_amdgcn_sched_barrier(0);
      }
    }
  }

  // C write: mf = q*2+mq -> rows (mf>>1)*64 + (mf&1)*32 + wr*16
#pragma unroll
  for (int mf = 0; mf < 8; ++mf) {
    const int r = row0 + (mf >> 1) * 64 + (mf & 1) * 32 + wr * 16 + hi * 4;
#pragma unroll
    for (int nf = 0; nf < 4; ++nf) {
      const int c = col0 + nf * 64 + wc * 16 + lr;
#pragma unroll
      for (int j = 0; j < 4; ++j)
        C[(size_t)(r + j) * N + c] = (bf16_t)acc[mf][nf][j];
    }
  }
}

// -------------------------------------------------------------- attention
// R7 kernel (best measured: 123 us), Q pitch = fused QKV buffer.
#define QB 128
#define KVB 64
#define PP 72    // Ps pitch 144B

__global__ __launch_bounds__(512, 2) void attn_kernel(
    const bf16_t* __restrict__ Q,   // [B*S][QKVP] (RAW fused projection)
    const bf16_t* __restrict__ Kt,  // [B][NKV][S][H] (roped)
    const bf16_t* __restrict__ Vt,  // [B][NKV][H][S]
    bf16_t* __restrict__ AV) {      // [B*S][NQ*H]
  __shared__ bf16_t Ks[2][KVB * SH];   // 2 x 32 KB, row pitch 512B
  __shared__ bf16_t Vs[2][SH * KVB];   // 2 x 32 KB, row pitch 128B
  __shared__ bf16_t Ps[QB * PP];       // 18 KB

  const int tid = threadIdx.x, lane = tid & 63, wid = tid >> 6;
  const int x = blockIdx.x & 7;
  const int y = blockIdx.x >> 3;       // 0..63
  const int qt = 15 - (y & 15);        // heavy tiles dispatch first
  const int head = (x << 1) | ((y >> 4) & 1);
  const int b = y >> 5;
  const int kvh = x;
  const int t0 = qt << 7;
  const int trw = t0 + wid * 16;       // this wave's first q row
  const int lr = lane & 15, hi = lane >> 4;
  const int lk = hi << 3;
  const int lq = hi;

  // Q load + fused RoPE + 1/16 scale (pair (c, c+128) = qf[ks], qf[ks+4])
  bf16x8 qf[8];
  {
    const bf16_t* qp = Q + ((size_t)(b * SS + trw + lr)) * QKVP + head * SH + lk;
#pragma unroll
    for (int ks = 0; ks < 8; ++ks) qf[ks] = *(const bf16x8*)(qp + ks * 32);
    const float tpos = (float)(trw + lr);
#pragma unroll
    for (int ks = 0; ks < 4; ++ks) {
      bf16x8 a = qf[ks], b2 = qf[ks + 4];
      bf16x8 ra, rb;
#pragma unroll
      for (int e = 0; e < 8; ++e) {
        float c_ = (float)(ks * 32 + lk + e);
        float inv = __expf(c_ * -0.07195578f);
        float fr = tpos * inv;
        float cs = __cosf(fr), sn = __sinf(fr);
        float x1 = (float)a[e], x2 = (float)b2[e];
        ra[e] = (bf16_t)((x1 * cs - x2 * sn) * 0.0625f);
        rb[e] = (bf16_t)((x2 * cs + x1 * sn) * 0.0625f);
      }
      qf[ks] = ra; qf[ks + 4] = rb;
    }
  }

  f32x4 o[16];
#pragma unroll
  for (int i = 0; i < 16; ++i) o[i] = f32x4{0.f, 0.f, 0.f, 0.f};
  float lsum[4] = {0.f, 0.f, 0.f, 0.f};

  const bf16_t* Kb = Kt + (size_t)(b * SNKV + kvh) * SS * SH;
  const bf16_t* Vb = Vt + (size_t)(b * SNKV + kvh) * SH * SS;

  const int sv0 = (t0 >= SWIN) ? ((t0 >> 6) - 16) : 0;
  const int sv1 = (t0 >> 6) + 1;

  auto stage = [&](int s0, int d) {
#pragma unroll
    for (int it = 0; it < 4; ++it) {
      const int f = tid + (it << 9);           // 0..2047
      {
        const int r = f >> 5, pc = f & 31;
        const int sc = pc ^ (r & 7);
        async_ld16(Kb + (size_t)(s0 + r) * SH + sc * 8, (char*)Ks[d] + f * 16);
      }
      {
        const int r = f >> 3, pc = f & 7;
        const int sc = pc ^ (r & 7);
        async_ld16(Vb + (size_t)r * SS + s0 + sc * 8, (char*)Vs[d] + f * 16);
      }
    }
  };

  stage(sv0 << 6, 0);
  __syncthreads();

  int cur = 0;
  for (int sv = sv0; sv <= sv1; ++sv, cur ^= 1) {
    if (sv < sv1) stage((sv + 1) << 6, cur ^ 1);

    const int s0 = sv << 6;
    const bool skip = (s0 > trw + 15) || (s0 + 63 < trw - (SWIN - 1));
    if (!skip) {
      const bf16_t* Kc = Ks[cur];
      const bf16_t* Vc = Vs[cur];
      f32x4 sacc[4];
#pragma unroll
      for (int nt = 0; nt < 4; ++nt) sacc[nt] = f32x4{0.f, 0.f, 0.f, 0.f};
      __builtin_amdgcn_s_setprio(1);
#pragma unroll
      for (int ks = 0; ks < 8; ++ks) {
#pragma unroll
        for (int nt = 0; nt < 4; ++nt) {
          const int R = nt * 16 + lr;
          bf16x8 kf = *(const bf16x8*)((const char*)Kc + R * 512 +
                                       (((ks * 4 + hi) ^ (R & 7)) << 4));
          sacc[nt] = __builtin_amdgcn_mfma_f32_16x16x32_bf16(qf[ks], kf, sacc[nt], 0, 0, 0);
        }
      }
      __builtin_amdgcn_s_setprio(0);

      const bool full = (s0 + 63 <= trw) && (s0 >= trw + 15 - (SWIN - 1));
      if (full) {
#pragma unroll
        for (int nt = 0; nt < 4; ++nt) {
#pragma unroll
          for (int j = 0; j < 4; ++j) {
            float u = sacc[nt][j] * 0.04f;
            float th = 50.f - 100.f * __builtin_amdgcn_rcpf(__expf(u) + 1.f);
            float p = __expf(th);
            lsum[j] += p;
            Ps[(wid * 16 + lq * 4 + j) * PP + nt * 16 + lr] = (bf16_t)p;
          }
        }
      } else {
#pragma unroll
        for (int nt = 0; nt < 4; ++nt) {
          const int s_ = s0 + nt * 16 + lr;
#pragma unroll
          for (int j = 0; j < 4; ++j) {
            const int t_ = trw + lq * 4 + j;
            float u = sacc[nt][j] * 0.04f;
            float th = 50.f - 100.f * __builtin_amdgcn_rcpf(__expf(u) + 1.f);
            const bool valid = (s_ <= t_) && (t_ - s_ < SWIN);
            float p = valid ? __expf(th) : 0.f;
            lsum[j] += p;
            Ps[(wid * 16 + lq * 4 + j) * PP + nt * 16 + lr] = (bf16_t)p;
          }
        }
      }

      __builtin_amdgcn_s_setprio(1);
#pragma unroll
      for (int ks = 0; ks < 2; ++ks) {
        bf16x8 pf = *(const bf16x8*)&Ps[(wid * 16 + lr) * PP + ks * 32 + lk];
#pragma unroll
        for (int nt = 0; nt < 16; ++nt) {
          const int R = nt * 16 + lr;
          bf16x8 vf = *(const bf16x8*)((const char*)Vc + R * 128 +
                                       (((ks * 4 + hi) ^ (R & 7)) << 4));
          o[nt] = __builtin_amdgcn_mfma_f32_16x16x32_bf16(pf, vf, o[nt], 0, 0, 0);
        }
      }
      __builtin_amdgcn_s_setprio(0);
    }

    __syncthreads();
  }

#pragma unroll
  for (int j = 0; j < 4; ++j) {
    float l = lsum[j];
    l += __shfl_xor(l, 1);
    l += __shfl_xor(l, 2);
    l += __shfl_xor(l, 4);
    l += __shfl_xor(l, 8);
    const float inv = 1.f / l;
    const int t_ = trw + lq * 4 + j;
    bf16_t* op = AV + ((size_t)(b * SS + t_)) * (SNQ * SH) + head * SH;
#pragma unroll
    for (int nt = 0; nt < 16; ++nt) op[nt * 16 + lr] = (bf16_t)(o[nt][j] * inv);
  }
}

// ------------------------------------------------------------------- host
extern "C" void kernel_launch(void* const* d_in, const int* in_sizes, int n_in,
                              void* d_out, int out_size, void* d_ws, size_t ws_size,
                              hipStream_t stream) {
  const float* x = (const float*)d_in[0];
  const float* Wq = (const float*)d_in[1];
  const float* Wk = (const float*)d_in[2];
  const float* Wv = (const float*)d_in[3];
  const float* Wo = (const float*)d_in[4];
  float* out = (float*)d_out;

  char* ws = (char*)d_ws;
  size_t off = 0;
  auto alloc = [&](size_t elems) {
    bf16_t* p = (bf16_t*)(ws + off);
    off += ((elems * 2 + 255) & ~(size_t)255);
    return p;
  };
  const size_t MS = (size_t)SB * SS;        // 4096 rows
  bf16_t* xb     = alloc(MS * SD);                 // [4096][2048]
  bf16_t* wqkvT  = alloc((size_t)QKVP * SD);       // [8192][2048]: Wq|Wk|Wv
  bf16_t* woT    = alloc((size_t)SD * SNQ * SH);   // [2048][4096]
  bf16_t* qkv    = alloc(MS * QKVP);               // [4096][8192]: Q|K|V
  bf16_t* kb     = alloc(MS * SNKV * SH);          // [B][NKV][S][H]
  bf16_t* vt     = alloc(MS * SNKV * SH);          // [B][NKV][H][S]
  bf16_t* av     = alloc(MS * SNQ * SH);           // [4096][4096]
  (void)ws_size;  // ~178 MB

  cvt_kernel<<<(MS * SD / 4) / 256, 256, 0, stream>>>(x, xb);
  wtrans_kernel<<<dim3(SH / 64, SD / 64, 16), 256, 0, stream>>>(Wq, wqkvT, SD, SH);
  wtrans_kernel<<<dim3(SH / 64, SD / 64, 8), 256, 0, stream>>>(Wk, wqkvT + (size_t)4096 * SD, SD, SH);
  wtrans_kernel<<<dim3(SH / 64, SD / 64, 8), 256, 0, stream>>>(Wv, wqkvT + (size_t)6144 * SD, SD, SH);
  wtrans_kernel<<<dim3(SD / 64, (SNQ * SH) / 64, 1), 256, 0, stream>>>(Wo, woT, SNQ * SH, SD);

  // fused Q|K|V projection on the 8-phase kernel: [4096x2048] x [8192x2048]^T
  gemm8p<<<512, 512, 0, stream>>>(xb, wqkvT, qkv, 4096, QKVP, 2048);

  rope_k_kernel<<<(MS * SNKV * 16) / 256, 256, 0, stream>>>(qkv, kb);
  vtrans_kernel<<<dim3(SH / 64, SS / 64, 16), 256, 0, stream>>>(qkv + 6144, vt);

  attn_kernel<<<512, 512, 0, stream>>>(qkv, kb, vt, av);

  gemm_bt<2, false><<<256, 512, 0, stream>>>(av, woT, out, 4096, 2048, 4096);
}

// Round 15
// 358.882 us; speedup vs baseline: 1.4052x; 1.0925x over previous
//
#include <hip/hip_runtime.h>
#include <stdint.h>

typedef __bf16 bf16_t;
typedef __bf16 bf16x8 __attribute__((ext_vector_type(8)));
typedef __bf16 bf16x4 __attribute__((ext_vector_type(4)));
typedef float f32x4 __attribute__((ext_vector_type(4)));

#define DEV static __device__ __forceinline__

// problem constants
#define SB 2
#define SS 2048
#define SD 2048
#define SNQ 16
#define SNKV 8
#define SH 256
#define SWIN 1024
#define QKVP 8192   // fused projection output pitch (Q | K | V)

DEV void async_ld16(const void* g, void* lds) {
  __builtin_amdgcn_global_load_lds(
      (const __attribute__((address_space(1))) void*)g,
      (__attribute__((address_space(3))) void*)lds, 16, 0, 0);
}

// ---------------------------------------------------------------- convert x
__global__ __launch_bounds__(256) void cvt_kernel(const float* __restrict__ in,
                                                  bf16_t* __restrict__ out) {
  int i = blockIdx.x * 256 + threadIdx.x;  // over n/4 elements
  float4 v = ((const float4*)in)[i];
  bf16x4 o = {(bf16_t)v.x, (bf16_t)v.y, (bf16_t)v.z, (bf16_t)v.w};
  *(bf16x4*)(out + (size_t)i * 4) = o;
}

// ------------------------------------------- batched transpose f32 -> bf16
// 64x64 tiles, vector global both directions, LDS transpose (144B pitch+XOR).
__global__ __launch_bounds__(256) void wtrans_kernel(const float* __restrict__ in,
                                                     bf16_t* __restrict__ out,
                                                     int R, int C) {
  __shared__ bf16_t T[64 * 72];
  const int bz = blockIdx.z;
  const float* ip = in + (size_t)bz * R * C;
  bf16_t* op = out + (size_t)bz * R * C;
  const int r0 = blockIdx.y * 64, c0 = blockIdx.x * 64;
  const int tc = threadIdx.x & 15;        // 16 x 4 f32 = 64 cols
  const int tr = threadIdx.x >> 4;        // 0..15
#pragma unroll
  for (int i = 0; i < 4; ++i) {
    const int r = tr + i * 16;
    float4 v = *(const float4*)(ip + (size_t)(r0 + r) * C + c0 + tc * 4);
    float vv[4] = {v.x, v.y, v.z, v.w};
#pragma unroll
    for (int e = 0; e < 4; ++e) {
      const int row = tc * 4 + e;         // transposed row (= input col)
      *(bf16_t*)((char*)T + row * 144 + ((r * 2) ^ (((row >> 3) & 7) << 4))) =
          (bf16_t)vv[e];
    }
  }
  __syncthreads();
  const int tc2 = threadIdx.x & 7, tr2 = threadIdx.x >> 3;  // 0..31
#pragma unroll
  for (int i = 0; i < 2; ++i) {
    const int row = tr2 + i * 32;
    bf16x8 v = *(const bf16x8*)((const char*)T + row * 144 +
                                ((tc2 * 16) ^ (((row >> 3) & 7) << 4)));
    *(bf16x8*)(op + (size_t)(c0 + row) * R + r0 + tc2 * 8) = v;
  }
}

// ------------------------------------------------- V transpose bf16 -> bf16
// qkv [B*S][8192] (V cols start at 6144) -> vt [b*8+kv][H][S].
__global__ __launch_bounds__(256) void vtrans_kernel(const bf16_t* __restrict__ vbase,
                                                     bf16_t* __restrict__ vt) {
  __shared__ bf16_t T[64 * 72];
  const int bz = blockIdx.z, b = bz >> 3, kv = bz & 7;
  const int t0 = blockIdx.y * 64, h0 = blockIdx.x * 64;
  const int tc = threadIdx.x & 7, tr = threadIdx.x >> 3;  // tr 0..31
  const bf16_t* ip = vbase + (size_t)b * SS * QKVP + kv * SH;
#pragma unroll
  for (int i = 0; i < 2; ++i) {
    const int t = tr + i * 32;
    bf16x8 v = *(const bf16x8*)(ip + (size_t)(t0 + t) * QKVP + h0 + tc * 8);
#pragma unroll
    for (int e = 0; e < 8; ++e) {
      const int row = tc * 8 + e;         // h-row in transposed tile
      *(bf16_t*)((char*)T + row * 144 + ((t * 2) ^ (((row >> 3) & 7) << 4))) = v[e];
    }
  }
  __syncthreads();
  bf16_t* op = vt + (size_t)bz * SH * SS;
#pragma unroll
  for (int i = 0; i < 2; ++i) {
    const int row = tr + i * 32;
    bf16x8 v = *(const bf16x8*)((const char*)T + row * 144 +
                                ((tc * 16) ^ (((row >> 3) & 7) << 4)));
    *(bf16x8*)(op + (size_t)(h0 + row) * SS + t0 + tc * 8) = v;
  }
}

// --------------------------------------------------------- RoPE-K (vector)
// qkv [B*S][8192] (K cols 4096..6143) -> kb [B][NKV][S][H] with rope.
__global__ __launch_bounds__(256) void rope_k_kernel(const bf16_t* __restrict__ qkv,
                                                     bf16_t* __restrict__ kb) {
  int idx = blockIdx.x * 256 + threadIdx.x;      // B*S*NKV*16
  const int i8 = (idx & 15) << 3;                // 0..120
  const int kv = (idx >> 4) & 7;
  const int row = idx >> 7;                      // 0..4095
  const int t = row & (SS - 1), b = row >> 11;
  const size_t ib = (size_t)row * QKVP + 4096 + kv * SH;
  bf16x8 x1 = *(const bf16x8*)(qkv + ib + i8);
  bf16x8 x2 = *(const bf16x8*)(qkv + ib + i8 + 128);
  bf16x8 r1, r2;
#pragma unroll
  for (int e = 0; e < 8; ++e) {
    float c_ = (float)(i8 + e);
    float inv = __expf(c_ * -0.07195578f);       // ln(10000)/128
    float fr = (float)t * inv;
    float cs = __cosf(fr), sn = __sinf(fr);
    float a = (float)x1[e], b2 = (float)x2[e];
    r1[e] = (bf16_t)(a * cs - b2 * sn);
    r2[e] = (bf16_t)(b2 * cs + a * sn);
  }
  const size_t ob = ((size_t)(b * SNKV + kv) * SS + t) * SH;
  *(bf16x8*)(kb + ob + i8) = r1;
  *(bf16x8*)(kb + ob + i8 + 128) = r2;
}

// ---------------------------------------- GEMM 8-phase (T2+T3+T4+T5)
// BM=256, BN in {256,128}, BK=64, 8 waves (WMxWN), 2-deep LDS dbuf.
// Interleaved frag layout: phase q touches only A rows 64q..64q+63, so
// staging half-tiles of t+1 one-per-phase allows COUNTED vmcnt:
//   vmcnt(4) before ph1-end barrier  (Ah1(t) landed for ph2/ph3 reads)
//   vmcnt(2) before ph3-end barrier  (first halves of t+1 landed)
// Only 2 barriers per K-tile (ph0/ph2-end barriers synchronize nothing).
// LDS swizzle (both sides): slot ^= (row & 7) at 128B row pitch.
// BN=256: grid 512 = 16x32, each XCD owns an 8x8 (by,bx) square.
// BN=128: grid 256 = 16x16, each XCD owns a 4x8 square.
template <int BN, bool OUT_BF16>
__global__ __launch_bounds__(512, 1) void gemm8p(const bf16_t* __restrict__ A,
                                                 const bf16_t* __restrict__ Bt,
                                                 void* __restrict__ Cout,
                                                 int M, int N, int K) {
  constexpr int WM = (BN == 256) ? 2 : 4;
  constexpr int WN = 8 / WM;
  constexpr int MQ = 4 / WM;          // m-frags per phase (2 or 1)
  constexpr int BH = BN / 128;        // B half-tiles per K-tile (2 or 1)
  __shared__ bf16_t As[2][256 * 64];  // 2 x 32 KB
  __shared__ bf16_t Bs[2][BN * 64];   // 2 x 32|16 KB

  const int tid = threadIdx.x, lane = tid & 63, wid = tid >> 6;
  const int xcd = blockIdx.x & 7, ii = blockIdx.x >> 3;
  int by, bx;
  if (BN == 256) { by = (xcd & 1) * 8 + (ii >> 3); bx = (xcd >> 1) * 8 + (ii & 7); }
  else           { by = (xcd & 3) * 4 + (ii >> 3); bx = (xcd >> 2) * 8 + (ii & 7); }
  const int row0 = by << 8, col0 = bx * BN;
  const int wr = wid / WN, wc = wid % WN;
  const int lr = lane & 15, hi = lane >> 4;

  const bf16_t* Arow = A + (size_t)row0 * K;
  const bf16_t* Brow = Bt + (size_t)col0 * K;

  // stage one 16KB half-tile (128 rows x 64 cols); dest linear f*16;
  // source col pre-swizzled: sc = pc ^ (r&7).
  auto stageHA = [&](int t, int h) {
#pragma unroll
    for (int i = 0; i < 2; ++i) {
      const int f = tid + (i << 9);
      const int r = (h << 7) + (f >> 3), pc = f & 7;
      async_ld16(Arow + (size_t)r * K + (t << 6) + (pc ^ (r & 7)) * 8,
                 (char*)As[t & 1] + (h << 14) + f * 16);
    }
  };
  auto stageHB = [&](int t, int h) {
#pragma unroll
    for (int i = 0; i < 2; ++i) {
      const int f = tid + (i << 9);
      const int r = (h << 7) + (f >> 3), pc = f & 7;
      async_ld16(Brow + (size_t)r * K + (t << 6) + (pc ^ (r & 7)) * 8,
                 (char*)Bs[t & 1] + (h << 14) + f * 16);
    }
  };

  f32x4 acc[4 * MQ][4];
#pragma unroll
  for (int m = 0; m < 4 * MQ; ++m)
#pragma unroll
    for (int n = 0; n < 4; ++n) acc[m][n] = f32x4{0.f, 0.f, 0.f, 0.f};

  const int NT = K >> 6;
  // prologue: stage tile 0; first 2|3 halves must land -> vmcnt(2)
  stageHB(0, 0);
  if (BH == 2) stageHB(0, 1);
  stageHA(0, 0); stageHA(0, 1);
  asm volatile("s_waitcnt vmcnt(2)" ::: "memory");
  __builtin_amdgcn_s_barrier();
  __builtin_amdgcn_sched_barrier(0);

  for (int t = 0; t < NT; ++t) {
    const bool pre = (t + 1 < NT);
    const char* Ab = (const char*)As[t & 1];
    const char* Bb = (const char*)Bs[t & 1];
    bf16x8 bfr[4][2];

#pragma unroll
    for (int q = 0; q < 4; ++q) {
      if (q == 0) {
#pragma unroll
        for (int nf = 0; nf < 4; ++nf)
#pragma unroll
          for (int ks = 0; ks < 2; ++ks) {
            const int r = nf * (16 * WN) + wc * 16 + lr;
            bfr[nf][ks] = *(const bf16x8*)(Bb + r * 128 +
                                           ((((ks << 2) + hi) ^ (r & 7)) << 4));
          }
      }
      bf16x8 af[MQ][2];
#pragma unroll
      for (int mq = 0; mq < MQ; ++mq)
#pragma unroll
        for (int ks = 0; ks < 2; ++ks) {
          const int r = q * 64 + mq * (16 * WM) + wr * 16 + lr;
          af[mq][ks] = *(const bf16x8*)(Ab + r * 128 +
                                        ((((ks << 2) + hi) ^ (r & 7)) << 4));
        }
      // issue next tile's half-tile stage (one per phase)
      if (pre) {
        if (BH == 2) {
          if (q == 0) stageHB(t + 1, 0);
          if (q == 1) stageHB(t + 1, 1);
          if (q == 2) stageHA(t + 1, 0);
          if (q == 3) stageHA(t + 1, 1);
        } else {
          if (q == 0) stageHB(t + 1, 0);
          if (q == 1) stageHA(t + 1, 0);
          if (q == 2) stageHA(t + 1, 1);
        }
      }
      asm volatile("s_waitcnt lgkmcnt(0)" ::: "memory");
      __builtin_amdgcn_sched_barrier(0);
      __builtin_amdgcn_s_setprio(1);
#pragma unroll
      for (int mq = 0; mq < MQ; ++mq)
#pragma unroll
        for (int nf = 0; nf < 4; ++nf)
#pragma unroll
          for (int ks = 0; ks < 2; ++ks)
            acc[q * MQ + mq][nf] = __builtin_amdgcn_mfma_f32_16x16x32_bf16(
                af[mq][ks], bfr[nf][ks], acc[q * MQ + mq][nf], 0, 0, 0);
      __builtin_amdgcn_s_setprio(0);
      // counted waits BEFORE barriers; only 2 barriers per tile
      if (q == 1) {
        if (pre) asm volatile("s_waitcnt vmcnt(4)" ::: "memory");
        else     asm volatile("s_waitcnt vmcnt(0)" ::: "memory");
        __builtin_amdgcn_s_barrier();
        __builtin_amdgcn_sched_barrier(0);
      }
      if (q == 3 && pre) {
        asm volatile("s_waitcnt vmcnt(2)" ::: "memory");
        __builtin_amdgcn_s_barrier();
        __builtin_amdgcn_sched_barrier(0);
      }
    }
  }

  // C write: acc[q*MQ+mq] -> rows q*64 + mq*(16*WM) + wr*16
#pragma unroll
  for (int mf = 0; mf < 4 * MQ; ++mf) {
    const int r = row0 + (mf / MQ) * 64 + (mf % MQ) * (16 * WM) + wr * 16 + hi * 4;
#pragma unroll
    for (int nf = 0; nf < 4; ++nf) {
      const int c = col0 + nf * (16 * WN) + wc * 16 + lr;
#pragma unroll
      for (int j = 0; j < 4; ++j) {
        if (OUT_BF16)
          ((bf16_t*)Cout)[(size_t)(r + j) * N + c] = (bf16_t)acc[mf][nf][j];
        else
          ((float*)Cout)[(size_t)(r + j) * N + c] = acc[mf][nf][j];
      }
    }
  }
}

// -------------------------------------------------------------- attention
// R7 kernel (best measured: 123 us), Q pitch = fused QKV buffer.
#define QB 128
#define KVB 64
#define PP 72    // Ps pitch 144B

__global__ __launch_bounds__(512, 2) void attn_kernel(
    const bf16_t* __restrict__ Q,   // [B*S][QKVP] (RAW fused projection)
    const bf16_t* __restrict__ Kt,  // [B][NKV][S][H] (roped)
    const bf16_t* __restrict__ Vt,  // [B][NKV][H][S]
    bf16_t* __restrict__ AV) {      // [B*S][NQ*H]
  __shared__ bf16_t Ks[2][KVB * SH];   // 2 x 32 KB, row pitch 512B
  __shared__ bf16_t Vs[2][SH * KVB];   // 2 x 32 KB, row pitch 128B
  __shared__ bf16_t Ps[QB * PP];       // 18 KB

  const int tid = threadIdx.x, lane = tid & 63, wid = tid >> 6;
  const int x = blockIdx.x & 7;
  const int y = blockIdx.x >> 3;       // 0..63
  const int qt = 15 - (y & 15);        // heavy tiles dispatch first
  const int head = (x << 1) | ((y >> 4) & 1);
  const int b = y >> 5;
  const int kvh = x;
  const int t0 = qt << 7;
  const int trw = t0 + wid * 16;       // this wave's first q row
  const int lr = lane & 15, hi = lane >> 4;
  const int lk = hi << 3;
  const int lq = hi;

  // Q load + fused RoPE + 1/16 scale (pair (c, c+128) = qf[ks], qf[ks+4])
  bf16x8 qf[8];
  {
    const bf16_t* qp = Q + ((size_t)(b * SS + trw + lr)) * QKVP + head * SH + lk;
#pragma unroll
    for (int ks = 0; ks < 8; ++ks) qf[ks] = *(const bf16x8*)(qp + ks * 32);
    const float tpos = (float)(trw + lr);
#pragma unroll
    for (int ks = 0; ks < 4; ++ks) {
      bf16x8 a = qf[ks], b2 = qf[ks + 4];
      bf16x8 ra, rb;
#pragma unroll
      for (int e = 0; e < 8; ++e) {
        float c_ = (float)(ks * 32 + lk + e);
        float inv = __expf(c_ * -0.07195578f);
        float fr = tpos * inv;
        float cs = __cosf(fr), sn = __sinf(fr);
        float x1 = (float)a[e], x2 = (float)b2[e];
        ra[e] = (bf16_t)((x1 * cs - x2 * sn) * 0.0625f);
        rb[e] = (bf16_t)((x2 * cs + x1 * sn) * 0.0625f);
      }
      qf[ks] = ra; qf[ks + 4] = rb;
    }
  }

  f32x4 o[16];
#pragma unroll
  for (int i = 0; i < 16; ++i) o[i] = f32x4{0.f, 0.f, 0.f, 0.f};
  float lsum[4] = {0.f, 0.f, 0.f, 0.f};

  const bf16_t* Kb = Kt + (size_t)(b * SNKV + kvh) * SS * SH;
  const bf16_t* Vb = Vt + (size_t)(b * SNKV + kvh) * SH * SS;

  const int sv0 = (t0 >= SWIN) ? ((t0 >> 6) - 16) : 0;
  const int sv1 = (t0 >> 6) + 1;

  auto stage = [&](int s0, int d) {
#pragma unroll
    for (int it = 0; it < 4; ++it) {
      const int f = tid + (it << 9);           // 0..2047
      {
        const int r = f >> 5, pc = f & 31;
        const int sc = pc ^ (r & 7);
        async_ld16(Kb + (size_t)(s0 + r) * SH + sc * 8, (char*)Ks[d] + f * 16);
      }
      {
        const int r = f >> 3, pc = f & 7;
        const int sc = pc ^ (r & 7);
        async_ld16(Vb + (size_t)r * SS + s0 + sc * 8, (char*)Vs[d] + f * 16);
      }
    }
  };

  stage(sv0 << 6, 0);
  __syncthreads();

  int cur = 0;
  for (int sv = sv0; sv <= sv1; ++sv, cur ^= 1) {
    if (sv < sv1) stage((sv + 1) << 6, cur ^ 1);

    const int s0 = sv << 6;
    const bool skip = (s0 > trw + 15) || (s0 + 63 < trw - (SWIN - 1));
    if (!skip) {
      const bf16_t* Kc = Ks[cur];
      const bf16_t* Vc = Vs[cur];
      f32x4 sacc[4];
#pragma unroll
      for (int nt = 0; nt < 4; ++nt) sacc[nt] = f32x4{0.f, 0.f, 0.f, 0.f};
      __builtin_amdgcn_s_setprio(1);
#pragma unroll
      for (int ks = 0; ks < 8; ++ks) {
#pragma unroll
        for (int nt = 0; nt < 4; ++nt) {
          const int R = nt * 16 + lr;
          bf16x8 kf = *(const bf16x8*)((const char*)Kc + R * 512 +
                                       (((ks * 4 + hi) ^ (R & 7)) << 4));
          sacc[nt] = __builtin_amdgcn_mfma_f32_16x16x32_bf16(qf[ks], kf, sacc[nt], 0, 0, 0);
        }
      }
      __builtin_amdgcn_s_setprio(0);

      const bool full = (s0 + 63 <= trw) && (s0 >= trw + 15 - (SWIN - 1));
      if (full) {
#pragma unroll
        for (int nt = 0; nt < 4; ++nt) {
#pragma unroll
          for (int j = 0; j < 4; ++j) {
            float u = sacc[nt][j] * 0.04f;
            float th = 50.f - 100.f * __builtin_amdgcn_rcpf(__expf(u) + 1.f);
            float p = __expf(th);
            lsum[j] += p;
            Ps[(wid * 16 + lq * 4 + j) * PP + nt * 16 + lr] = (bf16_t)p;
          }
        }
      } else {
#pragma unroll
        for (int nt = 0; nt < 4; ++nt) {
          const int s_ = s0 + nt * 16 + lr;
#pragma unroll
          for (int j = 0; j < 4; ++j) {
            const int t_ = trw + lq * 4 + j;
            float u = sacc[nt][j] * 0.04f;
            float th = 50.f - 100.f * __builtin_amdgcn_rcpf(__expf(u) + 1.f);
            const bool valid = (s_ <= t_) && (t_ - s_ < SWIN);
            float p = valid ? __expf(th) : 0.f;
            lsum[j] += p;
            Ps[(wid * 16 + lq * 4 + j) * PP + nt * 16 + lr] = (bf16_t)p;
          }
        }
      }

      __builtin_amdgcn_s_setprio(1);
#pragma unroll
      for (int ks = 0; ks < 2; ++ks) {
        bf16x8 pf = *(const bf16x8*)&Ps[(wid * 16 + lr) * PP + ks * 32 + lk];
#pragma unroll
        for (int nt = 0; nt < 16; ++nt) {
          const int R = nt * 16 + lr;
          bf16x8 vf = *(const bf16x8*)((const char*)Vc + R * 128 +
                                       (((ks * 4 + hi) ^ (R & 7)) << 4));
          o[nt] = __builtin_amdgcn_mfma_f32_16x16x32_bf16(pf, vf, o[nt], 0, 0, 0);
        }
      }
      __builtin_amdgcn_s_setprio(0);
    }

    __syncthreads();
  }

#pragma unroll
  for (int j = 0; j < 4; ++j) {
    float l = lsum[j];
    l += __shfl_xor(l, 1);
    l += __shfl_xor(l, 2);
    l += __shfl_xor(l, 4);
    l += __shfl_xor(l, 8);
    const float inv = 1.f / l;
    const int t_ = trw + lq * 4 + j;
    bf16_t* op = AV + ((size_t)(b * SS + t_)) * (SNQ * SH) + head * SH;
#pragma unroll
    for (int nt = 0; nt < 16; ++nt) op[nt * 16 + lr] = (bf16_t)(o[nt][j] * inv);
  }
}

// ------------------------------------------------------------------- host
extern "C" void kernel_launch(void* const* d_in, const int* in_sizes, int n_in,
                              void* d_out, int out_size, void* d_ws, size_t ws_size,
                              hipStream_t stream) {
  const float* x = (const float*)d_in[0];
  const float* Wq = (const float*)d_in[1];
  const float* Wk = (const float*)d_in[2];
  const float* Wv = (const float*)d_in[3];
  const float* Wo = (const float*)d_in[4];
  float* out = (float*)d_out;

  char* ws = (char*)d_ws;
  size_t off = 0;
  auto alloc = [&](size_t elems) {
    bf16_t* p = (bf16_t*)(ws + off);
    off += ((elems * 2 + 255) & ~(size_t)255);
    return p;
  };
  const size_t MS = (size_t)SB * SS;        // 4096 rows
  bf16_t* xb     = alloc(MS * SD);                 // [4096][2048]
  bf16_t* wqkvT  = alloc((size_t)QKVP * SD);       // [8192][2048]: Wq|Wk|Wv
  bf16_t* woT    = alloc((size_t)SD * SNQ * SH);   // [2048][4096]
  bf16_t* qkv    = alloc(MS * QKVP);               // [4096][8192]: Q|K|V
  bf16_t* kb     = alloc(MS * SNKV * SH);          // [B][NKV][S][H]
  bf16_t* vt     = alloc(MS * SNKV * SH);          // [B][NKV][H][S]
  bf16_t* av     = alloc(MS * SNQ * SH);           // [4096][4096]
  (void)ws_size;  // ~178 MB

  cvt_kernel<<<(MS * SD / 4) / 256, 256, 0, stream>>>(x, xb);
  wtrans_kernel<<<dim3(SH / 64, SD / 64, 16), 256, 0, stream>>>(Wq, wqkvT, SD, SH);
  wtrans_kernel<<<dim3(SH / 64, SD / 64, 8), 256, 0, stream>>>(Wk, wqkvT + (size_t)4096 * SD, SD, SH);
  wtrans_kernel<<<dim3(SH / 64, SD / 64, 8), 256, 0, stream>>>(Wv, wqkvT + (size_t)6144 * SD, SD, SH);
  wtrans_kernel<<<dim3(SD / 64, (SNQ * SH) / 64, 1), 256, 0, stream>>>(Wo, woT, SNQ * SH, SD);

  // fused Q|K|V projection: [4096x2048] x [8192x2048]^T -> [4096][8192]
  gemm8p<256, true><<<512, 512, 0, stream>>>(xb, wqkvT, qkv, 4096, QKVP, 2048);

  rope_k_kernel<<<(MS * SNKV * 16) / 256, 256, 0, stream>>>(qkv, kb);
  vtrans_kernel<<<dim3(SH / 64, SS / 64, 16), 256, 0, stream>>>(qkv + 6144, vt);

  attn_kernel<<<512, 512, 0, stream>>>(qkv, kb, vt, av);

  // O-proj: [4096x4096] x [2048x4096]^T -> [4096][2048] f32, 256 blocks
  gemm8p<128, false><<<256, 512, 0, stream>>>(av, woT, out, 4096, 2048, 4096);
}

// Round 16
// 358.091 us; speedup vs baseline: 1.4083x; 1.0022x over previous
//
#include <hip/hip_runtime.h>
#include <stdint.h>

typedef __bf16 bf16_t;
typedef __bf16 bf16x8 __attribute__((ext_vector_type(8)));
typedef __bf16 bf16x4 __attribute__((ext_vector_type(4)));
typedef float f32x4 __attribute__((ext_vector_type(4)));

#define DEV static __device__ __forceinline__

// problem constants
#define SB 2
#define SS 2048
#define SD 2048
#define SNQ 16
#define SNKV 8
#define SH 256
#define SWIN 1024
#define QKVP 8192   // fused projection output pitch (Q | K | V)

DEV void async_ld16(const void* g, void* lds) {
  __builtin_amdgcn_global_load_lds(
      (const __attribute__((address_space(1))) void*)g,
      (__attribute__((address_space(3))) void*)lds, 16, 0, 0);
}

// ---------------------------------------------------------------- convert x
__global__ __launch_bounds__(256) void cvt_kernel(const float* __restrict__ in,
                                                  bf16_t* __restrict__ out) {
  int i = blockIdx.x * 256 + threadIdx.x;  // over n/4 elements
  float4 v = ((const float4*)in)[i];
  bf16x4 o = {(bf16_t)v.x, (bf16_t)v.y, (bf16_t)v.z, (bf16_t)v.w};
  *(bf16x4*)(out + (size_t)i * 4) = o;
}

// ------------------------------------------- batched transpose f32 -> bf16
// 64x64 tiles, vector global both directions, LDS transpose (144B pitch+XOR).
__global__ __launch_bounds__(256) void wtrans_kernel(const float* __restrict__ in,
                                                     bf16_t* __restrict__ out,
                                                     int R, int C) {
  __shared__ bf16_t T[64 * 72];
  const int bz = blockIdx.z;
  const float* ip = in + (size_t)bz * R * C;
  bf16_t* op = out + (size_t)bz * R * C;
  const int r0 = blockIdx.y * 64, c0 = blockIdx.x * 64;
  const int tc = threadIdx.x & 15;        // 16 x 4 f32 = 64 cols
  const int tr = threadIdx.x >> 4;        // 0..15
#pragma unroll
  for (int i = 0; i < 4; ++i) {
    const int r = tr + i * 16;
    float4 v = *(const float4*)(ip + (size_t)(r0 + r) * C + c0 + tc * 4);
    float vv[4] = {v.x, v.y, v.z, v.w};
#pragma unroll
    for (int e = 0; e < 4; ++e) {
      const int row = tc * 4 + e;         // transposed row (= input col)
      *(bf16_t*)((char*)T + row * 144 + ((r * 2) ^ (((row >> 3) & 7) << 4))) =
          (bf16_t)vv[e];
    }
  }
  __syncthreads();
  const int tc2 = threadIdx.x & 7, tr2 = threadIdx.x >> 3;  // 0..31
#pragma unroll
  for (int i = 0; i < 2; ++i) {
    const int row = tr2 + i * 32;
    bf16x8 v = *(const bf16x8*)((const char*)T + row * 144 +
                                ((tc2 * 16) ^ (((row >> 3) & 7) << 4)));
    *(bf16x8*)(op + (size_t)(c0 + row) * R + r0 + tc2 * 8) = v;
  }
}

// ------------------------------------------------- V transpose bf16 -> bf16
// qkv [B*S][8192] (V cols start at 6144) -> vt [b*8+kv][H][S].
__global__ __launch_bounds__(256) void vtrans_kernel(const bf16_t* __restrict__ vbase,
                                                     bf16_t* __restrict__ vt) {
  __shared__ bf16_t T[64 * 72];
  const int bz = blockIdx.z, b = bz >> 3, kv = bz & 7;
  const int t0 = blockIdx.y * 64, h0 = blockIdx.x * 64;
  const int tc = threadIdx.x & 7, tr = threadIdx.x >> 3;  // tr 0..31
  const bf16_t* ip = vbase + (size_t)b * SS * QKVP + kv * SH;
#pragma unroll
  for (int i = 0; i < 2; ++i) {
    const int t = tr + i * 32;
    bf16x8 v = *(const bf16x8*)(ip + (size_t)(t0 + t) * QKVP + h0 + tc * 8);
#pragma unroll
    for (int e = 0; e < 8; ++e) {
      const int row = tc * 8 + e;         // h-row in transposed tile
      *(bf16_t*)((char*)T + row * 144 + ((t * 2) ^ (((row >> 3) & 7) << 4))) = v[e];
    }
  }
  __syncthreads();
  bf16_t* op = vt + (size_t)bz * SH * SS;
#pragma unroll
  for (int i = 0; i < 2; ++i) {
    const int row = tr + i * 32;
    bf16x8 v = *(const bf16x8*)((const char*)T + row * 144 +
                                ((tc * 16) ^ (((row >> 3) & 7) << 4)));
    *(bf16x8*)(op + (size_t)(h0 + row) * SS + t0 + tc * 8) = v;
  }
}

// --------------------------------------------------------- RoPE-K (vector)
// qkv [B*S][8192] (K cols 4096..6143) -> kb [B][NKV][S][H] with rope.
__global__ __launch_bounds__(256) void rope_k_kernel(const bf16_t* __restrict__ qkv,
                                                     bf16_t* __restrict__ kb) {
  int idx = blockIdx.x * 256 + threadIdx.x;      // B*S*NKV*16
  const int i8 = (idx & 15) << 3;                // 0..120
  const int kv = (idx >> 4) & 7;
  const int row = idx >> 7;                      // 0..4095
  const int t = row & (SS - 1), b = row >> 11;
  const size_t ib = (size_t)row * QKVP + 4096 + kv * SH;
  bf16x8 x1 = *(const bf16x8*)(qkv + ib + i8);
  bf16x8 x2 = *(const bf16x8*)(qkv + ib + i8 + 128);
  bf16x8 r1, r2;
#pragma unroll
  for (int e = 0; e < 8; ++e) {
    float c_ = (float)(i8 + e);
    float inv = __expf(c_ * -0.07195578f);       // ln(10000)/128
    float fr = (float)t * inv;
    float cs = __cosf(fr), sn = __sinf(fr);
    float a = (float)x1[e], b2 = (float)x2[e];
    r1[e] = (bf16_t)(a * cs - b2 * sn);
    r2[e] = (bf16_t)(b2 * cs + a * sn);
  }
  const size_t ob = ((size_t)(b * SNKV + kv) * SS + t) * SH;
  *(bf16x8*)(kb + ob + i8) = r1;
  *(bf16x8*)(kb + ob + i8 + 128) = r2;
}

// ---------------------------------------- GEMM 8-phase (T2+T3+T4+T5)
// BM=256, BN in {256,128}, BK=64, 8 waves (WMxWN), 2-deep LDS dbuf.
// Interleaved frag layout: phase q touches only A rows 64q..64q+63, so
// staging half-tiles of t+1 one-per-phase allows COUNTED vmcnt:
//   vmcnt(4) before ph1-end barrier  (Ah1(t) landed for ph2/ph3 reads)
//   vmcnt(2) before ph3-end barrier  (first halves of t+1 landed)
// Only 2 barriers per K-tile. NO per-phase lgkmcnt: ds_reads are plain C++
// loads, so the compiler inserts precise lgkmcnt(N) per use and is free to
// hoist the next phase's reads under this phase's MFMA cluster (the two
// phases inside each barrier region pipeline automatically).
// LDS swizzle (both sides): slot ^= (row & 7) at 128B row pitch.
// BN=256: grid 512 = 16x32, each XCD owns an 8x8 (by,bx) square.
// BN=128: grid 256 = 16x16, each XCD owns a 4x8 square.
template <int BN, bool OUT_BF16>
__global__ __launch_bounds__(512, 1) void gemm8p(const bf16_t* __restrict__ A,
                                                 const bf16_t* __restrict__ Bt,
                                                 void* __restrict__ Cout,
                                                 int M, int N, int K) {
  constexpr int WM = (BN == 256) ? 2 : 4;
  constexpr int WN = 8 / WM;
  constexpr int MQ = 4 / WM;          // m-frags per phase (2 or 1)
  constexpr int BH = BN / 128;        // B half-tiles per K-tile (2 or 1)
  __shared__ bf16_t As[2][256 * 64];  // 2 x 32 KB
  __shared__ bf16_t Bs[2][BN * 64];   // 2 x 32|16 KB

  const int tid = threadIdx.x, lane = tid & 63, wid = tid >> 6;
  const int xcd = blockIdx.x & 7, ii = blockIdx.x >> 3;
  int by, bx;
  if (BN == 256) { by = (xcd & 1) * 8 + (ii >> 3); bx = (xcd >> 1) * 8 + (ii & 7); }
  else           { by = (xcd & 3) * 4 + (ii >> 3); bx = (xcd >> 2) * 8 + (ii & 7); }
  const int row0 = by << 8, col0 = bx * BN;
  const int wr = wid / WN, wc = wid % WN;
  const int lr = lane & 15, hi = lane >> 4;

  const bf16_t* Arow = A + (size_t)row0 * K;
  const bf16_t* Brow = Bt + (size_t)col0 * K;

  // stage one 16KB half-tile (128 rows x 64 cols); dest linear f*16;
  // source col pre-swizzled: sc = pc ^ (r&7).
  auto stageHA = [&](int t, int h) {
#pragma unroll
    for (int i = 0; i < 2; ++i) {
      const int f = tid + (i << 9);
      const int r = (h << 7) + (f >> 3), pc = f & 7;
      async_ld16(Arow + (size_t)r * K + (t << 6) + (pc ^ (r & 7)) * 8,
                 (char*)As[t & 1] + (h << 14) + f * 16);
    }
  };
  auto stageHB = [&](int t, int h) {
#pragma unroll
    for (int i = 0; i < 2; ++i) {
      const int f = tid + (i << 9);
      const int r = (h << 7) + (f >> 3), pc = f & 7;
      async_ld16(Brow + (size_t)r * K + (t << 6) + (pc ^ (r & 7)) * 8,
                 (char*)Bs[t & 1] + (h << 14) + f * 16);
    }
  };

  f32x4 acc[4 * MQ][4];
#pragma unroll
  for (int m = 0; m < 4 * MQ; ++m)
#pragma unroll
    for (int n = 0; n < 4; ++n) acc[m][n] = f32x4{0.f, 0.f, 0.f, 0.f};

  const int NT = K >> 6;
  // prologue: stage tile 0; first 2|3 halves must land -> vmcnt(2)
  stageHB(0, 0);
  if (BH == 2) stageHB(0, 1);
  stageHA(0, 0); stageHA(0, 1);
  asm volatile("s_waitcnt vmcnt(2)" ::: "memory");
  __builtin_amdgcn_s_barrier();
  __builtin_amdgcn_sched_barrier(0);

  for (int t = 0; t < NT; ++t) {
    const bool pre = (t + 1 < NT);
    const char* Ab = (const char*)As[t & 1];
    const char* Bb = (const char*)Bs[t & 1];
    bf16x8 bfr[4][2];

#pragma unroll
    for (int q = 0; q < 4; ++q) {
      if (q == 0) {
#pragma unroll
        for (int nf = 0; nf < 4; ++nf)
#pragma unroll
          for (int ks = 0; ks < 2; ++ks) {
            const int r = nf * (16 * WN) + wc * 16 + lr;
            bfr[nf][ks] = *(const bf16x8*)(Bb + r * 128 +
                                           ((((ks << 2) + hi) ^ (r & 7)) << 4));
          }
      }
      bf16x8 af[MQ][2];
#pragma unroll
      for (int mq = 0; mq < MQ; ++mq)
#pragma unroll
        for (int ks = 0; ks < 2; ++ks) {
          const int r = q * 64 + mq * (16 * WM) + wr * 16 + lr;
          af[mq][ks] = *(const bf16x8*)(Ab + r * 128 +
                                        ((((ks << 2) + hi) ^ (r & 7)) << 4));
        }
      // issue next tile's half-tile stage (one per phase)
      if (pre) {
        if (BH == 2) {
          if (q == 0) stageHB(t + 1, 0);
          if (q == 1) stageHB(t + 1, 1);
          if (q == 2) stageHA(t + 1, 0);
          if (q == 3) stageHA(t + 1, 1);
        } else {
          if (q == 0) stageHB(t + 1, 0);
          if (q == 1) stageHA(t + 1, 0);
          if (q == 2) stageHA(t + 1, 1);
        }
      }
      __builtin_amdgcn_s_setprio(1);
#pragma unroll
      for (int mq = 0; mq < MQ; ++mq)
#pragma unroll
        for (int nf = 0; nf < 4; ++nf)
#pragma unroll
          for (int ks = 0; ks < 2; ++ks)
            acc[q * MQ + mq][nf] = __builtin_amdgcn_mfma_f32_16x16x32_bf16(
                af[mq][ks], bfr[nf][ks], acc[q * MQ + mq][nf], 0, 0, 0);
      __builtin_amdgcn_s_setprio(0);
      // counted waits BEFORE barriers; only 2 barriers per tile
      if (q == 1) {
        if (pre) asm volatile("s_waitcnt vmcnt(4)" ::: "memory");
        else     asm volatile("s_waitcnt vmcnt(0)" ::: "memory");
        __builtin_amdgcn_s_barrier();
        __builtin_amdgcn_sched_barrier(0);
      }
      if (q == 3 && pre) {
        asm volatile("s_waitcnt vmcnt(2)" ::: "memory");
        __builtin_amdgcn_s_barrier();
        __builtin_amdgcn_sched_barrier(0);
      }
    }
  }

  // C write: acc[q*MQ+mq] -> rows q*64 + mq*(16*WM) + wr*16
#pragma unroll
  for (int mf = 0; mf < 4 * MQ; ++mf) {
    const int r = row0 + (mf / MQ) * 64 + (mf % MQ) * (16 * WM) + wr * 16 + hi * 4;
#pragma unroll
    for (int nf = 0; nf < 4; ++nf) {
      const int c = col0 + nf * (16 * WN) + wc * 16 + lr;
#pragma unroll
      for (int j = 0; j < 4; ++j) {
        if (OUT_BF16)
          ((bf16_t*)Cout)[(size_t)(r + j) * N + c] = (bf16_t)acc[mf][nf][j];
        else
          ((float*)Cout)[(size_t)(r + j) * N + c] = acc[mf][nf][j];
      }
    }
  }
}

// -------------------------------------------------------------- attention
// R7 kernel (best measured: 123 us), Q pitch = fused QKV buffer.
#define QB 128
#define KVB 64
#define PP 72    // Ps pitch 144B

__global__ __launch_bounds__(512, 2) void attn_kernel(
    const bf16_t* __restrict__ Q,   // [B*S][QKVP] (RAW fused projection)
    const bf16_t* __restrict__ Kt,  // [B][NKV][S][H] (roped)
    const bf16_t* __restrict__ Vt,  // [B][NKV][H][S]
    bf16_t* __restrict__ AV) {      // [B*S][NQ*H]
  __shared__ bf16_t Ks[2][KVB * SH];   // 2 x 32 KB, row pitch 512B
  __shared__ bf16_t Vs[2][SH * KVB];   // 2 x 32 KB, row pitch 128B
  __shared__ bf16_t Ps[QB * PP];       // 18 KB

  const int tid = threadIdx.x, lane = tid & 63, wid = tid >> 6;
  const int x = blockIdx.x & 7;
  const int y = blockIdx.x >> 3;       // 0..63
  const int qt = 15 - (y & 15);        // heavy tiles dispatch first
  const int head = (x << 1) | ((y >> 4) & 1);
  const int b = y >> 5;
  const int kvh = x;
  const int t0 = qt << 7;
  const int trw = t0 + wid * 16;       // this wave's first q row
  const int lr = lane & 15, hi = lane >> 4;
  const int lk = hi << 3;
  const int lq = hi;

  // Q load + fused RoPE + 1/16 scale (pair (c, c+128) = qf[ks], qf[ks+4])
  bf16x8 qf[8];
  {
    const bf16_t* qp = Q + ((size_t)(b * SS + trw + lr)) * QKVP + head * SH + lk;
#pragma unroll
    for (int ks = 0; ks < 8; ++ks) qf[ks] = *(const bf16x8*)(qp + ks * 32);
    const float tpos = (float)(trw + lr);
#pragma unroll
    for (int ks = 0; ks < 4; ++ks) {
      bf16x8 a = qf[ks], b2 = qf[ks + 4];
      bf16x8 ra, rb;
#pragma unroll
      for (int e = 0; e < 8; ++e) {
        float c_ = (float)(ks * 32 + lk + e);
        float inv = __expf(c_ * -0.07195578f);
        float fr = tpos * inv;
        float cs = __cosf(fr), sn = __sinf(fr);
        float x1 = (float)a[e], x2 = (float)b2[e];
        ra[e] = (bf16_t)((x1 * cs - x2 * sn) * 0.0625f);
        rb[e] = (bf16_t)((x2 * cs + x1 * sn) * 0.0625f);
      }
      qf[ks] = ra; qf[ks + 4] = rb;
    }
  }

  f32x4 o[16];
#pragma unroll
  for (int i = 0; i < 16; ++i) o[i] = f32x4{0.f, 0.f, 0.f, 0.f};
  float lsum[4] = {0.f, 0.f, 0.f, 0.f};

  const bf16_t* Kb = Kt + (size_t)(b * SNKV + kvh) * SS * SH;
  const bf16_t* Vb = Vt + (size_t)(b * SNKV + kvh) * SH * SS;

  const int sv0 = (t0 >= SWIN) ? ((t0 >> 6) - 16) : 0;
  const int sv1 = (t0 >> 6) + 1;

  auto stage = [&](int s0, int d) {
#pragma unroll
    for (int it = 0; it < 4; ++it) {
      const int f = tid + (it << 9);           // 0..2047
      {
        const int r = f >> 5, pc = f & 31;
        const int sc = pc ^ (r & 7);
        async_ld16(Kb + (size_t)(s0 + r) * SH + sc * 8, (char*)Ks[d] + f * 16);
      }
      {
        const int r = f >> 3, pc = f & 7;
        const int sc = pc ^ (r & 7);
        async_ld16(Vb + (size_t)r * SS + s0 + sc * 8, (char*)Vs[d] + f * 16);
      }
    }
  };

  stage(sv0 << 6, 0);
  __syncthreads();

  int cur = 0;
  for (int sv = sv0; sv <= sv1; ++sv, cur ^= 1) {
    if (sv < sv1) stage((sv + 1) << 6, cur ^ 1);

    const int s0 = sv << 6;
    const bool skip = (s0 > trw + 15) || (s0 + 63 < trw - (SWIN - 1));
    if (!skip) {
      const bf16_t* Kc = Ks[cur];
      const bf16_t* Vc = Vs[cur];
      f32x4 sacc[4];
#pragma unroll
      for (int nt = 0; nt < 4; ++nt) sacc[nt] = f32x4{0.f, 0.f, 0.f, 0.f};
      __builtin_amdgcn_s_setprio(1);
#pragma unroll
      for (int ks = 0; ks < 8; ++ks) {
#pragma unroll
        for (int nt = 0; nt < 4; ++nt) {
          const int R = nt * 16 + lr;
          bf16x8 kf = *(const bf16x8*)((const char*)Kc + R * 512 +
                                       (((ks * 4 + hi) ^ (R & 7)) << 4));
          sacc[nt] = __builtin_amdgcn_mfma_f32_16x16x32_bf16(qf[ks], kf, sacc[nt], 0, 0, 0);
        }
      }
      __builtin_amdgcn_s_setprio(0);

      const bool full = (s0 + 63 <= trw) && (s0 >= trw + 15 - (SWIN - 1));
      if (full) {
#pragma unroll
        for (int nt = 0; nt < 4; ++nt) {
#pragma unroll
          for (int j = 0; j < 4; ++j) {
            float u = sacc[nt][j] * 0.04f;
            float th = 50.f - 100.f * __builtin_amdgcn_rcpf(__expf(u) + 1.f);
            float p = __expf(th);
            lsum[j] += p;
            Ps[(wid * 16 + lq * 4 + j) * PP + nt * 16 + lr] = (bf16_t)p;
          }
        }
      } else {
#pragma unroll
        for (int nt = 0; nt < 4; ++nt) {
          const int s_ = s0 + nt * 16 + lr;
#pragma unroll
          for (int j = 0; j < 4; ++j) {
            const int t_ = trw + lq * 4 + j;
            float u = sacc[nt][j] * 0.04f;
            float th = 50.f - 100.f * __builtin_amdgcn_rcpf(__expf(u) + 1.f);
            const bool valid = (s_ <= t_) && (t_ - s_ < SWIN);
            float p = valid ? __expf(th) : 0.f;
            lsum[j] += p;
            Ps[(wid * 16 + lq * 4 + j) * PP + nt * 16 + lr] = (bf16_t)p;
          }
        }
      }

      __builtin_amdgcn_s_setprio(1);
#pragma unroll
      for (int ks = 0; ks < 2; ++ks) {
        bf16x8 pf = *(const bf16x8*)&Ps[(wid * 16 + lr) * PP + ks * 32 + lk];
#pragma unroll
        for (int nt = 0; nt < 16; ++nt) {
          const int R = nt * 16 + lr;
          bf16x8 vf = *(const bf16x8*)((const char*)Vc + R * 128 +
                                       (((ks * 4 + hi) ^ (R & 7)) << 4));
          o[nt] = __builtin_amdgcn_mfma_f32_16x16x32_bf16(pf, vf, o[nt], 0, 0, 0);
        }
      }
      __builtin_amdgcn_s_setprio(0);
    }

    __syncthreads();
  }

#pragma unroll
  for (int j = 0; j < 4; ++j) {
    float l = lsum[j];
    l += __shfl_xor(l, 1);
    l += __shfl_xor(l, 2);
    l += __shfl_xor(l, 4);
    l += __shfl_xor(l, 8);
    const float inv = 1.f / l;
    const int t_ = trw + lq * 4 + j;
    bf16_t* op = AV + ((size_t)(b * SS + t_)) * (SNQ * SH) + head * SH;
#pragma unroll
    for (int nt = 0; nt < 16; ++nt) op[nt * 16 + lr] = (bf16_t)(o[nt][j] * inv);
  }
}

// ------------------------------------------------------------------- host
extern "C" void kernel_launch(void* const* d_in, const int* in_sizes, int n_in,
                              void* d_out, int out_size, void* d_ws, size_t ws_size,
                              hipStream_t stream) {
  const float* x = (const float*)d_in[0];
  const float* Wq = (const float*)d_in[1];
  const float* Wk = (const float*)d_in[2];
  const float* Wv = (const float*)d_in[3];
  const float* Wo = (const float*)d_in[4];
  float* out = (float*)d_out;

  char* ws = (char*)d_ws;
  size_t off = 0;
  auto alloc = [&](size_t elems) {
    bf16_t* p = (bf16_t*)(ws + off);
    off += ((elems * 2 + 255) & ~(size_t)255);
    return p;
  };
  const size_t MS = (size_t)SB * SS;        // 4096 rows
  bf16_t* xb     = alloc(MS * SD);                 // [4096][2048]
  bf16_t* wqkvT  = alloc((size_t)QKVP * SD);       // [8192][2048]: Wq|Wk|Wv
  bf16_t* woT    = alloc((size_t)SD * SNQ * SH);   // [2048][4096]
  bf16_t* qkv    = alloc(MS * QKVP);               // [4096][8192]: Q|K|V
  bf16_t* kb     = alloc(MS * SNKV * SH);          // [B][NKV][S][H]
  bf16_t* vt     = alloc(MS * SNKV * SH);          // [B][NKV][H][S]
  bf16_t* av     = alloc(MS * SNQ * SH);           // [4096][4096]
  (void)ws_size;  // ~178 MB

  cvt_kernel<<<(MS * SD / 4) / 256, 256, 0, stream>>>(x, xb);
  wtrans_kernel<<<dim3(SH / 64, SD / 64, 16), 256, 0, stream>>>(Wq, wqkvT, SD, SH);
  wtrans_kernel<<<dim3(SH / 64, SD / 64, 8), 256, 0, stream>>>(Wk, wqkvT + (size_t)4096 * SD, SD, SH);
  wtrans_kernel<<<dim3(SH / 64, SD / 64, 8), 256, 0, stream>>>(Wv, wqkvT + (size_t)6144 * SD, SD, SH);
  wtrans_kernel<<<dim3(SD / 64, (SNQ * SH) / 64, 1), 256, 0, stream>>>(Wo, woT, SNQ * SH, SD);

  // fused Q|K|V projection: [4096x2048] x [8192x2048]^T -> [4096][8192]
  gemm8p<256, true><<<512, 512, 0, stream>>>(xb, wqkvT, qkv, 4096, QKVP, 2048);

  rope_k_kernel<<<(MS * SNKV * 16) / 256, 256, 0, stream>>>(qkv, kb);
  vtrans_kernel<<<dim3(SH / 64, SS / 64, 16), 256, 0, stream>>>(qkv + 6144, vt);

  attn_kernel<<<512, 512, 0, stream>>>(qkv, kb, vt, av);

  // O-proj: [4096x4096] x [2048x4096]^T -> [4096][2048] f32, 256 blocks
  gemm8p<128, false><<<256, 512, 0, stream>>>(av, woT, out, 4096, 2048, 4096);
}

// Round 17
// 347.108 us; speedup vs baseline: 1.4528x; 1.0316x over previous
//
#include <hip/hip_runtime.h>
#include <stdint.h>

typedef __bf16 bf16_t;
typedef __bf16 bf16x8 __attribute__((ext_vector_type(8)));
typedef __bf16 bf16x4 __attribute__((ext_vector_type(4)));
typedef float f32x4 __attribute__((ext_vector_type(4)));

#define DEV static __device__ __forceinline__

// problem constants
#define SB 2
#define SS 2048
#define SD 2048
#define SNQ 16
#define SNKV 8
#define SH 256
#define SWIN 1024
#define QKVP 8192   // fused projection output pitch (Q | K | V)

DEV void async_ld16(const void* g, void* lds) {
  __builtin_amdgcn_global_load_lds(
      (const __attribute__((address_space(1))) void*)g,
      (__attribute__((address_space(3))) void*)lds, 16, 0, 0);
}

// ---------------------------------------------------------------- convert x
__global__ __launch_bounds__(256) void cvt_kernel(const float* __restrict__ in,
                                                  bf16_t* __restrict__ out) {
  int i = blockIdx.x * 256 + threadIdx.x;  // over n/4 elements
  float4 v = ((const float4*)in)[i];
  bf16x4 o = {(bf16_t)v.x, (bf16_t)v.y, (bf16_t)v.z, (bf16_t)v.w};
  *(bf16x4*)(out + (size_t)i * 4) = o;
}

// ------------------------------------------- batched transpose f32 -> bf16
// 64x64 tiles, vector global both directions, LDS transpose (144B pitch+XOR).
// Merged QKV variant: z 0..15 -> Wq, 16..23 -> Wk, 24..31 -> Wv; output rows
// at 256*z of wqkvT. R=2048, C=256 fixed.
__global__ __launch_bounds__(256) void wtrans3_kernel(const float* __restrict__ Wq,
                                                      const float* __restrict__ Wk,
                                                      const float* __restrict__ Wv,
                                                      bf16_t* __restrict__ out) {
  __shared__ bf16_t T[64 * 72];
  const int zg = blockIdx.z;
  const float* ip = (zg < 16) ? (Wq + (size_t)zg * SD * SH)
                  : (zg < 24) ? (Wk + (size_t)(zg - 16) * SD * SH)
                              : (Wv + (size_t)(zg - 24) * SD * SH);
  bf16_t* op = out + (size_t)zg * SD * SH;
  const int r0 = blockIdx.y * 64, c0 = blockIdx.x * 64;
  const int tc = threadIdx.x & 15;        // 16 x 4 f32 = 64 cols
  const int tr = threadIdx.x >> 4;        // 0..15
#pragma unroll
  for (int i = 0; i < 4; ++i) {
    const int r = tr + i * 16;
    float4 v = *(const float4*)(ip + (size_t)(r0 + r) * SH + c0 + tc * 4);
    float vv[4] = {v.x, v.y, v.z, v.w};
#pragma unroll
    for (int e = 0; e < 4; ++e) {
      const int row = tc * 4 + e;         // transposed row (= input col)
      *(bf16_t*)((char*)T + row * 144 + ((r * 2) ^ (((row >> 3) & 7) << 4))) =
          (bf16_t)vv[e];
    }
  }
  __syncthreads();
  const int tc2 = threadIdx.x & 7, tr2 = threadIdx.x >> 3;  // 0..31
#pragma unroll
  for (int i = 0; i < 2; ++i) {
    const int row = tr2 + i * 32;
    bf16x8 v = *(const bf16x8*)((const char*)T + row * 144 +
                                ((tc2 * 16) ^ (((row >> 3) & 7) << 4)));
    *(bf16x8*)(op + (size_t)(c0 + row) * SD + r0 + tc2 * 8) = v;
  }
}

// generic single-tensor wtrans (for Wo)
__global__ __launch_bounds__(256) void wtrans_kernel(const float* __restrict__ in,
                                                     bf16_t* __restrict__ out,
                                                     int R, int C) {
  __shared__ bf16_t T[64 * 72];
  const float* ip = in;
  bf16_t* op = out;
  const int r0 = blockIdx.y * 64, c0 = blockIdx.x * 64;
  const int tc = threadIdx.x & 15;
  const int tr = threadIdx.x >> 4;
#pragma unroll
  for (int i = 0; i < 4; ++i) {
    const int r = tr + i * 16;
    float4 v = *(const float4*)(ip + (size_t)(r0 + r) * C + c0 + tc * 4);
    float vv[4] = {v.x, v.y, v.z, v.w};
#pragma unroll
    for (int e = 0; e < 4; ++e) {
      const int row = tc * 4 + e;
      *(bf16_t*)((char*)T + row * 144 + ((r * 2) ^ (((row >> 3) & 7) << 4))) =
          (bf16_t)vv[e];
    }
  }
  __syncthreads();
  const int tc2 = threadIdx.x & 7, tr2 = threadIdx.x >> 3;
#pragma unroll
  for (int i = 0; i < 2; ++i) {
    const int row = tr2 + i * 32;
    bf16x8 v = *(const bf16x8*)((const char*)T + row * 144 +
                                ((tc2 * 16) ^ (((row >> 3) & 7) << 4)));
    *(bf16x8*)(op + (size_t)(c0 + row) * R + r0 + tc2 * 8) = v;
  }
}

// ------------------------------------------------- V transpose bf16 -> bf16
// qkv [B*S][8192] (V cols start at 6144) -> vt [b*8+kv][H][S].
__global__ __launch_bounds__(256) void vtrans_kernel(const bf16_t* __restrict__ vbase,
                                                     bf16_t* __restrict__ vt) {
  __shared__ bf16_t T[64 * 72];
  const int bz = blockIdx.z, b = bz >> 3, kv = bz & 7;
  const int t0 = blockIdx.y * 64, h0 = blockIdx.x * 64;
  const int tc = threadIdx.x & 7, tr = threadIdx.x >> 3;  // tr 0..31
  const bf16_t* ip = vbase + (size_t)b * SS * QKVP + kv * SH;
#pragma unroll
  for (int i = 0; i < 2; ++i) {
    const int t = tr + i * 32;
    bf16x8 v = *(const bf16x8*)(ip + (size_t)(t0 + t) * QKVP + h0 + tc * 8);
#pragma unroll
    for (int e = 0; e < 8; ++e) {
      const int row = tc * 8 + e;         // h-row in transposed tile
      *(bf16_t*)((char*)T + row * 144 + ((t * 2) ^ (((row >> 3) & 7) << 4))) = v[e];
    }
  }
  __syncthreads();
  bf16_t* op = vt + (size_t)bz * SH * SS;
#pragma unroll
  for (int i = 0; i < 2; ++i) {
    const int row = tr + i * 32;
    bf16x8 v = *(const bf16x8*)((const char*)T + row * 144 +
                                ((tc * 16) ^ (((row >> 3) & 7) << 4)));
    *(bf16x8*)(op + (size_t)(h0 + row) * SS + t0 + tc * 8) = v;
  }
}

// ---------------------------------------- GEMM 8-phase (T2+T3+T4+T5)
// BM=256, BN in {256,128}, BK=64, 8 waves (WMxWN), 2-deep LDS dbuf.
// Counted vmcnt: vmcnt(4) before ph1-end barrier, vmcnt(2) before ph3-end
// barrier; 2 barriers per K-tile. LDS swizzle: slot ^= (row&7), 128B pitch.
// MODE: 0 = bf16 out, 1 = fused QKV (K-head blocks get RoPE applied in the
// epilogue and are written to kb [B][NKV][S][H] instead of qkv), 2 = f32 out.
template <int BN, int MODE>
__global__ __launch_bounds__(512, 1) void gemm8p(const bf16_t* __restrict__ A,
                                                 const bf16_t* __restrict__ Bt,
                                                 void* __restrict__ Cout,
                                                 bf16_t* __restrict__ kbp,
                                                 int M, int N, int K) {
  constexpr int WM = (BN == 256) ? 2 : 4;
  constexpr int WN = 8 / WM;
  constexpr int MQ = 4 / WM;          // m-frags per phase (2 or 1)
  constexpr int BH = BN / 128;        // B half-tiles per K-tile (2 or 1)
  __shared__ bf16_t As[2][256 * 64];  // 2 x 32 KB
  __shared__ bf16_t Bs[2][BN * 64];   // 2 x 32|16 KB

  const int tid = threadIdx.x, lane = tid & 63, wid = tid >> 6;
  const int xcd = blockIdx.x & 7, ii = blockIdx.x >> 3;
  int by, bx;
  if (BN == 256) { by = (xcd & 1) * 8 + (ii >> 3); bx = (xcd >> 1) * 8 + (ii & 7); }
  else           { by = (xcd & 3) * 4 + (ii >> 3); bx = (xcd >> 2) * 8 + (ii & 7); }
  const int row0 = by << 8, col0 = bx * BN;
  const int wr = wid / WN, wc = wid % WN;
  const int lr = lane & 15, hi = lane >> 4;

  const bf16_t* Arow = A + (size_t)row0 * K;
  const bf16_t* Brow = Bt + (size_t)col0 * K;

  auto stageHA = [&](int t, int h) {
#pragma unroll
    for (int i = 0; i < 2; ++i) {
      const int f = tid + (i << 9);
      const int r = (h << 7) + (f >> 3), pc = f & 7;
      async_ld16(Arow + (size_t)r * K + (t << 6) + (pc ^ (r & 7)) * 8,
                 (char*)As[t & 1] + (h << 14) + f * 16);
    }
  };
  auto stageHB = [&](int t, int h) {
#pragma unroll
    for (int i = 0; i < 2; ++i) {
      const int f = tid + (i << 9);
      const int r = (h << 7) + (f >> 3), pc = f & 7;
      async_ld16(Brow + (size_t)r * K + (t << 6) + (pc ^ (r & 7)) * 8,
                 (char*)Bs[t & 1] + (h << 14) + f * 16);
    }
  };

  f32x4 acc[4 * MQ][4];
#pragma unroll
  for (int m = 0; m < 4 * MQ; ++m)
#pragma unroll
    for (int n = 0; n < 4; ++n) acc[m][n] = f32x4{0.f, 0.f, 0.f, 0.f};

  const int NT = K >> 6;
  stageHB(0, 0);
  if (BH == 2) stageHB(0, 1);
  stageHA(0, 0); stageHA(0, 1);
  asm volatile("s_waitcnt vmcnt(2)" ::: "memory");
  __builtin_amdgcn_s_barrier();
  __builtin_amdgcn_sched_barrier(0);

  for (int t = 0; t < NT; ++t) {
    const bool pre = (t + 1 < NT);
    const char* Ab = (const char*)As[t & 1];
    const char* Bb = (const char*)Bs[t & 1];
    bf16x8 bfr[4][2];

#pragma unroll
    for (int q = 0; q < 4; ++q) {
      if (q == 0) {
#pragma unroll
        for (int nf = 0; nf < 4; ++nf)
#pragma unroll
          for (int ks = 0; ks < 2; ++ks) {
            const int r = nf * (16 * WN) + wc * 16 + lr;
            bfr[nf][ks] = *(const bf16x8*)(Bb + r * 128 +
                                           ((((ks << 2) + hi) ^ (r & 7)) << 4));
          }
      }
      bf16x8 af[MQ][2];
#pragma unroll
      for (int mq = 0; mq < MQ; ++mq)
#pragma unroll
        for (int ks = 0; ks < 2; ++ks) {
          const int r = q * 64 + mq * (16 * WM) + wr * 16 + lr;
          af[mq][ks] = *(const bf16x8*)(Ab + r * 128 +
                                        ((((ks << 2) + hi) ^ (r & 7)) << 4));
        }
      if (pre) {
        if (BH == 2) {
          if (q == 0) stageHB(t + 1, 0);
          if (q == 1) stageHB(t + 1, 1);
          if (q == 2) stageHA(t + 1, 0);
          if (q == 3) stageHA(t + 1, 1);
        } else {
          if (q == 0) stageHB(t + 1, 0);
          if (q == 1) stageHA(t + 1, 0);
          if (q == 2) stageHA(t + 1, 1);
        }
      }
      __builtin_amdgcn_s_setprio(1);
#pragma unroll
      for (int mq = 0; mq < MQ; ++mq)
#pragma unroll
        for (int nf = 0; nf < 4; ++nf)
#pragma unroll
          for (int ks = 0; ks < 2; ++ks)
            acc[q * MQ + mq][nf] = __builtin_amdgcn_mfma_f32_16x16x32_bf16(
                af[mq][ks], bfr[nf][ks], acc[q * MQ + mq][nf], 0, 0, 0);
      __builtin_amdgcn_s_setprio(0);
      if (q == 1) {
        if (pre) asm volatile("s_waitcnt vmcnt(4)" ::: "memory");
        else     asm volatile("s_waitcnt vmcnt(0)" ::: "memory");
        __builtin_amdgcn_s_barrier();
        __builtin_amdgcn_sched_barrier(0);
      }
      if (q == 3 && pre) {
        asm volatile("s_waitcnt vmcnt(2)" ::: "memory");
        __builtin_amdgcn_s_barrier();
        __builtin_amdgcn_sched_barrier(0);
      }
    }
  }

  // ---------------- epilogue ----------------
  if (MODE == 1 && bx >= 16 && bx < 24) {
    // K-head block: apply RoPE in-register, write to kb [B][NKV][S][H].
    // Pair: acc[mf][nfp] (h = nfp*64+wc*16+lr < 128) with acc[mf][nfp+2]
    // (h+128). t = global row & 2047, b = row >> 11.
    const int kv = bx - 16;
#pragma unroll
    for (int mf = 0; mf < 4 * MQ; ++mf) {
      const int r = row0 + (mf / MQ) * 64 + (mf % MQ) * (16 * WM) + wr * 16 + hi * 4;
#pragma unroll
      for (int nfp = 0; nfp < 2; ++nfp) {
        const int h = nfp * 64 + wc * 16 + lr;   // 0..127
        const float inv = __expf((float)h * -0.07195578f);
#pragma unroll
        for (int j = 0; j < 4; ++j) {
          const int rg = r + j;
          const int tpos = rg & (SS - 1), b = rg >> 11;
          const float fr = (float)tpos * inv;
          const float cs = __cosf(fr), sn = __sinf(fr);
          const float x1 = acc[mf][nfp][j], x2 = acc[mf][nfp + 2][j];
          bf16_t* kp = kbp + ((size_t)(b * SNKV + kv) * SS + tpos) * SH + h;
          kp[0] = (bf16_t)(x1 * cs - x2 * sn);
          kp[128] = (bf16_t)(x2 * cs + x1 * sn);
        }
      }
    }
  } else {
#pragma unroll
    for (int mf = 0; mf < 4 * MQ; ++mf) {
      const int r = row0 + (mf / MQ) * 64 + (mf % MQ) * (16 * WM) + wr * 16 + hi * 4;
#pragma unroll
      for (int nf = 0; nf < 4; ++nf) {
        const int c = col0 + nf * (16 * WN) + wc * 16 + lr;
#pragma unroll
        for (int j = 0; j < 4; ++j) {
          if (MODE == 2)
            ((float*)Cout)[(size_t)(r + j) * N + c] = acc[mf][nf][j];
          else
            ((bf16_t*)Cout)[(size_t)(r + j) * N + c] = (bf16_t)acc[mf][nf][j];
        }
      }
    }
  }
}

// -------------------------------------------------------------- attention
// R7 kernel (best measured: 123 us), Q pitch = fused QKV buffer.
#define QB 128
#define KVB 64
#define PP 72    // Ps pitch 144B

__global__ __launch_bounds__(512, 2) void attn_kernel(
    const bf16_t* __restrict__ Q,   // [B*S][QKVP] (RAW fused projection)
    const bf16_t* __restrict__ Kt,  // [B][NKV][S][H] (roped)
    const bf16_t* __restrict__ Vt,  // [B][NKV][H][S]
    bf16_t* __restrict__ AV) {      // [B*S][NQ*H]
  __shared__ bf16_t Ks[2][KVB * SH];   // 2 x 32 KB, row pitch 512B
  __shared__ bf16_t Vs[2][SH * KVB];   // 2 x 32 KB, row pitch 128B
  __shared__ bf16_t Ps[QB * PP];       // 18 KB

  const int tid = threadIdx.x, lane = tid & 63, wid = tid >> 6;
  const int x = blockIdx.x & 7;
  const int y = blockIdx.x >> 3;       // 0..63
  const int qt = 15 - (y & 15);        // heavy tiles dispatch first
  const int head = (x << 1) | ((y >> 4) & 1);
  const int b = y >> 5;
  const int kvh = x;
  const int t0 = qt << 7;
  const int trw = t0 + wid * 16;       // this wave's first q row
  const int lr = lane & 15, hi = lane >> 4;
  const int lk = hi << 3;
  const int lq = hi;

  // Q load + fused RoPE + 1/16 scale (pair (c, c+128) = qf[ks], qf[ks+4])
  bf16x8 qf[8];
  {
    const bf16_t* qp = Q + ((size_t)(b * SS + trw + lr)) * QKVP + head * SH + lk;
#pragma unroll
    for (int ks = 0; ks < 8; ++ks) qf[ks] = *(const bf16x8*)(qp + ks * 32);
    const float tpos = (float)(trw + lr);
#pragma unroll
    for (int ks = 0; ks < 4; ++ks) {
      bf16x8 a = qf[ks], b2 = qf[ks + 4];
      bf16x8 ra, rb;
#pragma unroll
      for (int e = 0; e < 8; ++e) {
        float c_ = (float)(ks * 32 + lk + e);
        float inv = __expf(c_ * -0.07195578f);
        float fr = tpos * inv;
        float cs = __cosf(fr), sn = __sinf(fr);
        float x1 = (float)a[e], x2 = (float)b2[e];
        ra[e] = (bf16_t)((x1 * cs - x2 * sn) * 0.0625f);
        rb[e] = (bf16_t)((x2 * cs + x1 * sn) * 0.0625f);
      }
      qf[ks] = ra; qf[ks + 4] = rb;
    }
  }

  f32x4 o[16];
#pragma unroll
  for (int i = 0; i < 16; ++i) o[i] = f32x4{0.f, 0.f, 0.f, 0.f};
  float lsum[4] = {0.f, 0.f, 0.f, 0.f};

  const bf16_t* Kb = Kt + (size_t)(b * SNKV + kvh) * SS * SH;
  const bf16_t* Vb = Vt + (size_t)(b * SNKV + kvh) * SH * SS;

  const int sv0 = (t0 >= SWIN) ? ((t0 >> 6) - 16) : 0;
  const int sv1 = (t0 >> 6) + 1;

  auto stage = [&](int s0, int d) {
#pragma unroll
    for (int it = 0; it < 4; ++it) {
      const int f = tid + (it << 9);           // 0..2047
      {
        const int r = f >> 5, pc = f & 31;
        const int sc = pc ^ (r & 7);
        async_ld16(Kb + (size_t)(s0 + r) * SH + sc * 8, (char*)Ks[d] + f * 16);
      }
      {
        const int r = f >> 3, pc = f & 7;
        const int sc = pc ^ (r & 7);
        async_ld16(Vb + (size_t)r * SS + s0 + sc * 8, (char*)Vs[d] + f * 16);
      }
    }
  };

  stage(sv0 << 6, 0);
  __syncthreads();

  int cur = 0;
  for (int sv = sv0; sv <= sv1; ++sv, cur ^= 1) {
    if (sv < sv1) stage((sv + 1) << 6, cur ^ 1);

    const int s0 = sv << 6;
    const bool skip = (s0 > trw + 15) || (s0 + 63 < trw - (SWIN - 1));
    if (!skip) {
      const bf16_t* Kc = Ks[cur];
      const bf16_t* Vc = Vs[cur];
      f32x4 sacc[4];
#pragma unroll
      for (int nt = 0; nt < 4; ++nt) sacc[nt] = f32x4{0.f, 0.f, 0.f, 0.f};
      __builtin_amdgcn_s_setprio(1);
#pragma unroll
      for (int ks = 0; ks < 8; ++ks) {
#pragma unroll
        for (int nt = 0; nt < 4; ++nt) {
          const int R = nt * 16 + lr;
          bf16x8 kf = *(const bf16x8*)((const char*)Kc + R * 512 +
                                       (((ks * 4 + hi) ^ (R & 7)) << 4));
          sacc[nt] = __builtin_amdgcn_mfma_f32_16x16x32_bf16(qf[ks], kf, sacc[nt], 0, 0, 0);
        }
      }
      __builtin_amdgcn_s_setprio(0);

      const bool full = (s0 + 63 <= trw) && (s0 >= trw + 15 - (SWIN - 1));
      if (full) {
#pragma unroll
        for (int nt = 0; nt < 4; ++nt) {
#pragma unroll
          for (int j = 0; j < 4; ++j) {
            float u = sacc[nt][j] * 0.04f;
            float th = 50.f - 100.f * __builtin_amdgcn_rcpf(__expf(u) + 1.f);
            float p = __expf(th);
            lsum[j] += p;
            Ps[(wid * 16 + lq * 4 + j) * PP + nt * 16 + lr] = (bf16_t)p;
          }
        }
      } else {
#pragma unroll
        for (int nt = 0; nt < 4; ++nt) {
          const int s_ = s0 + nt * 16 + lr;
#pragma unroll
          for (int j = 0; j < 4; ++j) {
            const int t_ = trw + lq * 4 + j;
            float u = sacc[nt][j] * 0.04f;
            float th = 50.f - 100.f * __builtin_amdgcn_rcpf(__expf(u) + 1.f);
            const bool valid = (s_ <= t_) && (t_ - s_ < SWIN);
            float p = valid ? __expf(th) : 0.f;
            lsum[j] += p;
            Ps[(wid * 16 + lq * 4 + j) * PP + nt * 16 + lr] = (bf16_t)p;
          }
        }
      }

      __builtin_amdgcn_s_setprio(1);
#pragma unroll
      for (int ks = 0; ks < 2; ++ks) {
        bf16x8 pf = *(const bf16x8*)&Ps[(wid * 16 + lr) * PP + ks * 32 + lk];
#pragma unroll
        for (int nt = 0; nt < 16; ++nt) {
          const int R = nt * 16 + lr;
          bf16x8 vf = *(const bf16x8*)((const char*)Vc + R * 128 +
                                       (((ks * 4 + hi) ^ (R & 7)) << 4));
          o[nt] = __builtin_amdgcn_mfma_f32_16x16x32_bf16(pf, vf, o[nt], 0, 0, 0);
        }
      }
      __builtin_amdgcn_s_setprio(0);
    }

    __syncthreads();
  }

#pragma unroll
  for (int j = 0; j < 4; ++j) {
    float l = lsum[j];
    l += __shfl_xor(l, 1);
    l += __shfl_xor(l, 2);
    l += __shfl_xor(l, 4);
    l += __shfl_xor(l, 8);
    const float inv = 1.f / l;
    const int t_ = trw + lq * 4 + j;
    bf16_t* op = AV + ((size_t)(b * SS + t_)) * (SNQ * SH) + head * SH;
#pragma unroll
    for (int nt = 0; nt < 16; ++nt) op[nt * 16 + lr] = (bf16_t)(o[nt][j] * inv);
  }
}

// ------------------------------------------------------------------- host
extern "C" void kernel_launch(void* const* d_in, const int* in_sizes, int n_in,
                              void* d_out, int out_size, void* d_ws, size_t ws_size,
                              hipStream_t stream) {
  const float* x = (const float*)d_in[0];
  const float* Wq = (const float*)d_in[1];
  const float* Wk = (const float*)d_in[2];
  const float* Wv = (const float*)d_in[3];
  const float* Wo = (const float*)d_in[4];
  float* out = (float*)d_out;

  char* ws = (char*)d_ws;
  size_t off = 0;
  auto alloc = [&](size_t elems) {
    bf16_t* p = (bf16_t*)(ws + off);
    off += ((elems * 2 + 255) & ~(size_t)255);
    return p;
  };
  const size_t MS = (size_t)SB * SS;        // 4096 rows
  bf16_t* xb     = alloc(MS * SD);                 // [4096][2048]
  bf16_t* wqkvT  = alloc((size_t)QKVP * SD);       // [8192][2048]: Wq|Wk|Wv
  bf16_t* woT    = alloc((size_t)SD * SNQ * SH);   // [2048][4096]
  bf16_t* qkv    = alloc(MS * QKVP);               // [4096][8192]: Q|·|V
  bf16_t* kb     = alloc(MS * SNKV * SH);          // [B][NKV][S][H] (roped)
  bf16_t* vt     = alloc(MS * SNKV * SH);          // [B][NKV][H][S]
  bf16_t* av     = alloc(MS * SNQ * SH);           // [4096][4096]
  (void)ws_size;  // ~178 MB

  cvt_kernel<<<(MS * SD / 4) / 256, 256, 0, stream>>>(x, xb);
  wtrans3_kernel<<<dim3(SH / 64, SD / 64, 32), 256, 0, stream>>>(Wq, Wk, Wv, wqkvT);
  wtrans_kernel<<<dim3(SD / 64, (SNQ * SH) / 64, 1), 256, 0, stream>>>(Wo, woT, SNQ * SH, SD);

  // fused Q|K|V projection; K heads roped in epilogue -> kb directly
  gemm8p<256, 1><<<512, 512, 0, stream>>>(xb, wqkvT, qkv, kb, 4096, QKVP, 2048);

  vtrans_kernel<<<dim3(SH / 64, SS / 64, 16), 256, 0, stream>>>(qkv + 6144, vt);

  attn_kernel<<<512, 512, 0, stream>>>(qkv, kb, vt, av);

  // O-proj: [4096x4096] x [2048x4096]^T -> [4096][2048] f32, 256 blocks
  gemm8p<128, 2><<<256, 512, 0, stream>>>(av, woT, out, nullptr, 4096, 2048, 4096);
}